// Round 2
// baseline (667.985 us; speedup 1.0000x reference)
//
#include <hip/hip_runtime.h>
#include <math.h>

#define N_TOK 4096
#define DIM 256
#define NHEAD 4
#define DPH 64
#define NEXP 9
#define SCALE 0.25f
#define MAXST 80    // 64-row supertiles: <= 64 + 9
#define GPAD 4736   // 64-aligned grouped rows upper bound
#define VPITCH 4736
#define NSPLIT 2    // key-range splits per (supertile, head)
#define GRID_X 768  // 3 blocks/CU x 256 CUs; launch_bounds(256,3) guarantees
#define NPROJ 960   // MAXST*4*3 proj units (2-pass loop over GRID_X)
#define NATTN 640   // MAXST*NHEAD*NSPLIT attn units (single pass)

typedef short s8 __attribute__((ext_vector_type(8)));
typedef short s4 __attribute__((ext_vector_type(4)));
typedef float f4 __attribute__((ext_vector_type(4)));

struct P {
  const float* x;
  const int* label;
  const float *Wq, *Wk, *Wv, *Wf;
  const float *bq, *bk, *bv;
  const float *bfv, *gamma, *beta;
  float* out;
  int *perm, *iperm, *gs, *gep, *st_e, *st_row, *nstp;
  short *qg, *kg, *vgT, *WbT, *xb;
  float *Op, *lp;
};

// One LDS arena, re-purposed per phase (each grid sync includes a block
// barrier, so reuse is safe). Max member = attn: 27648 B.
union SMem {
  struct { int cnt[4][NEXP]; int gsh[NEXP]; } b0;          // prep block 0
  short tile[64 * 68];                                     // prep transpose
  short st[4][16 * 72];                                    // proj store-transpose
  struct { short k[64 * 72]; short v[64 * 72]; short p[4 * 16 * 72]; } at;
  float h[16 * 260];                                       // out LN staging
};

// ---------------------------------------------------------------------------
// Hand-rolled grid barrier (no cooperative launch). Sense-reversing
// generation barrier in device globals: zero-init at module load,
// self-resetting (cnt returns to 0 after each barrier) so it is correct
// across graph replays with no per-launch initialization. AGENT-scope
// acq/rel atomics emit the L2 writeback/invalidate needed for cross-XCD
// visibility of plain stores (same mechanism as __ockl_grid_sync).
// Correct only because all GRID_X blocks are co-resident:
// launch_bounds(256,3) -> VGPR<=168, LDS 3x27648=83KB -> 3 blocks/CU x 256.
// ---------------------------------------------------------------------------
__device__ unsigned g_cnt = 0;
__device__ unsigned g_gen = 0;

static __device__ __forceinline__ void grid_sync() {
  __syncthreads();
  if (threadIdx.x == 0) {
    __threadfence();  // belt: release prior writes (fetch_add below also rel)
    unsigned gen =
        __hip_atomic_load(&g_gen, __ATOMIC_RELAXED, __HIP_MEMORY_SCOPE_AGENT);
    unsigned old = __hip_atomic_fetch_add(&g_cnt, 1u, __ATOMIC_ACQ_REL,
                                          __HIP_MEMORY_SCOPE_AGENT);
    if (old == GRID_X - 1) {
      __hip_atomic_store(&g_cnt, 0u, __ATOMIC_RELAXED,
                         __HIP_MEMORY_SCOPE_AGENT);
      __hip_atomic_fetch_add(&g_gen, 1u, __ATOMIC_RELEASE,
                             __HIP_MEMORY_SCOPE_AGENT);
    } else {
      while (__hip_atomic_load(&g_gen, __ATOMIC_ACQUIRE,
                               __HIP_MEMORY_SCOPE_AGENT) == gen) {
        __builtin_amdgcn_s_sleep(1);
      }
    }
    __threadfence();  // belt: acquire side
  }
  __syncthreads();
}

static __device__ __forceinline__ short f2bf(float f) {
  union { float f; unsigned u; } v;
  v.f = f;
  unsigned r = (v.u + 0x7FFFu + ((v.u >> 16) & 1u)) >> 16;
  return (short)r;
}

static __device__ __forceinline__ float wave_sum(float v) {
#pragma unroll
  for (int o = 32; o > 0; o >>= 1) v += __shfl_xor(v, o, 64);
  return v;
}

// ---------------------------------------------------------------------------
// Phase A: prep. Unit 0: atomic-free bucketing (ballot histogram + rank
// scatter). Units 1..448: W fp32 [d][h] -> WbT bf16 [slab][h][d]. Units
// 449..512: x -> bf16 cast. Units 513..767 idle.
// ---------------------------------------------------------------------------
static __device__ void phase_prep(const P& pp, SMem* sm, int b) {
  int tid = threadIdx.x;
  if (b == 0) {
    int wl = tid >> 6, lane = tid & 63;
    int lab[16];
#pragma unroll
    for (int i = 0; i < 16; i++) lab[i] = pp.label[wl * 1024 + i * 64 + lane];

    int cw[NEXP];
#pragma unroll
    for (int e = 0; e < NEXP; e++) cw[e] = 0;
#pragma unroll
    for (int i = 0; i < 16; i++)
#pragma unroll
      for (int e = 0; e < NEXP; e++)
        cw[e] += __popcll(__ballot(lab[i] == e));
    if (lane == 0)
#pragma unroll
      for (int e = 0; e < NEXP; e++) sm->b0.cnt[wl][e] = cw[e];
    __syncthreads();

    if (tid == 0) {
      int run = 0, ns = 0;
      for (int e = 0; e < NEXP; e++) {
        int tot = sm->b0.cnt[0][e] + sm->b0.cnt[1][e] + sm->b0.cnt[2][e] +
                  sm->b0.cnt[3][e];
        pp.gs[e] = run;
        sm->b0.gsh[e] = run;
        int end = run + tot;
        pp.gep[e] = end;
        for (int r = run; r < end; r += 64) {
          pp.st_e[ns] = e;
          pp.st_row[ns] = r;
          ns++;
        }
        run = (end + 63) & ~63;  // 64-align next group start
      }
      *pp.nstp = ns;
    }
    __syncthreads();

    int baseW[NEXP];
#pragma unroll
    for (int e = 0; e < NEXP; e++) {
      int bse = sm->b0.gsh[e];
      for (int w = 0; w < 4; w++)
        if (w < wl) bse += sm->b0.cnt[w][e];
      baseW[e] = bse;
    }
    int run2[NEXP];
#pragma unroll
    for (int e = 0; e < NEXP; e++) run2[e] = 0;
#pragma unroll
    for (int i = 0; i < 16; i++) {
      int t = wl * 1024 + i * 64 + lane;
      int lv = lab[i];
      unsigned long long below = (1ull << lane) - 1ull;
      int pos = 0;
#pragma unroll
      for (int e = 0; e < NEXP; e++) {
        unsigned long long mk = __ballot(lv == e);
        if (lv == e) pos = baseW[e] + run2[e] + __popcll(mk & below);
        run2[e] += __popcll(mk);
      }
      pp.perm[pos] = t;
      pp.iperm[t] = pos;
    }
  } else if (b <= 448) {
    // Weight transpose: slabs 0-8 Wq, 9-17 Wk, 18-26 Wv, 27 Wf; 16 tiles/slab.
    int vt = b - 1;
    int slab = vt >> 4;
    const float* src = (slab < 9)    ? pp.Wq + (size_t)slab * 65536
                       : (slab < 18) ? pp.Wk + (size_t)(slab - 9) * 65536
                       : (slab < 27) ? pp.Wv + (size_t)(slab - 18) * 65536
                                     : pp.Wf;
    int xy = vt & 15;
    int d0 = (xy >> 2) * 64, h0 = (xy & 3) * 64;
    int rl = tid >> 4;
    int hh = (tid & 15) * 4;
#pragma unroll
    for (int pq = 0; pq < 4; pq++) {
      int dl = pq * 16 + rl;
      float4 v = *(const float4*)(src + (size_t)(d0 + dl) * 256 + h0 + hh);
      s4 o;
      o[0] = f2bf(v.x); o[1] = f2bf(v.y); o[2] = f2bf(v.z); o[3] = f2bf(v.w);
      *(s4*)&sm->tile[dl * 68 + hh] = o;
    }
    __syncthreads();
    int hcol = tid >> 2, dq = (tid & 3) * 16;
    s8 pa, pb;
#pragma unroll
    for (int i = 0; i < 8; i++) {
      pa[i] = sm->tile[(dq + i) * 68 + hcol];
      pb[i] = sm->tile[(dq + 8 + i) * 68 + hcol];
    }
    short* dst =
        pp.WbT + (size_t)slab * 65536 + (size_t)(h0 + hcol) * 256 + d0 + dq;
    *(s8*)dst = pa;
    *(s8*)(dst + 8) = pb;
  } else if (b <= 512) {
    // x -> bf16, token order.
    int tok = (b - 449) * 64 + (tid >> 2);
    int qd = (tid & 3) * 64;
    const float* src = pp.x + (size_t)tok * DIM + qd;
    short* dst = pp.xb + (size_t)tok * DIM + qd;
#pragma unroll
    for (int i = 0; i < 16; i++) {
      float4 v = *(const float4*)(src + i * 4);
      s4 o;
      o[0] = f2bf(v.x); o[1] = f2bf(v.y); o[2] = f2bf(v.z); o[3] = f2bf(v.w);
      *(s4*)(dst + i * 4) = o;
    }
  }
}

// ---------------------------------------------------------------------------
// Phase B: MFMA QKV projection. Unit u -> (mtx, gy, supertile); wave = 16
// grouped rows x 64 cols; A-frags gathered via perm (clamped).
// ---------------------------------------------------------------------------
static __device__ void phase_proj(const P& pp, SMem* sm, int u) {
  int mtx = u / (MAXST * 4);
  int rem = u - mtx * (MAXST * 4);
  int gy = rem / MAXST;
  int bst = rem - gy * MAXST;
  if (bst >= *pp.nstp) return;
  int e = pp.st_e[bst];
  int row0 = pp.st_row[bst];
  int g1 = pp.gep[e];
  int tid = threadIdx.x, wl = tid >> 6, lane = tid & 63;
  int m = lane & 15, quad = lane >> 4;

  int row = row0 + wl * 16 + m;
  int pr = pp.perm[(row < g1) ? row : row0];  // clamp padding rows
  const short* Ap = pp.xb + (size_t)pr * DIM + quad * 8;
  const short* Bp = pp.WbT + (size_t)(mtx * 9 + e) * 65536 +
                    (size_t)(gy * 64 + m) * 256 + quad * 8;
  const float* bias = (mtx == 0) ? pp.bq : (mtx == 1) ? pp.bk : pp.bv;

  s8 ac = *(const s8*)Ap;
  s8 bc[4];
#pragma unroll
  for (int t = 0; t < 4; t++) bc[t] = *(const s8*)(Bp + t * 16 * 256);
  f4 acc[4];
#pragma unroll
  for (int t = 0; t < 4; t++) acc[t] = (f4){0.f, 0.f, 0.f, 0.f};
#pragma unroll
  for (int kc = 0; kc < 8; kc++) {
    s8 an = ac;
    s8 bn[4] = {bc[0], bc[1], bc[2], bc[3]};
    if (kc < 7) {
      an = *(const s8*)(Ap + (kc + 1) * 32);
#pragma unroll
      for (int t = 0; t < 4; t++)
        bn[t] = *(const s8*)(Bp + t * 16 * 256 + (kc + 1) * 32);
    }
#pragma unroll
    for (int t = 0; t < 4; t++)
      acc[t] = __builtin_amdgcn_mfma_f32_16x16x32_bf16(ac, bc[t], acc[t], 0, 0, 0);
    ac = an;
#pragma unroll
    for (int t = 0; t < 4; t++) bc[t] = bn[t];
  }

  if (mtx == 2) {
    // vgT[col][grow]: quad owns 4 consecutive grows per col -> 8B s4 stores.
#pragma unroll
    for (int t = 0; t < 4; t++) {
      int col = gy * 64 + t * 16 + m;
      float bs = bias[e * DIM + col];
      s4 o;
#pragma unroll
      for (int r = 0; r < 4; r++) o[r] = f2bf(acc[t][r] + bs);
      *(s4*)&pp.vgT[(size_t)col * VPITCH + row0 + wl * 16 + quad * 4] = o;
    }
  } else {
    // LDS transpose: C-layout -> [row][col] bf16, then coalesced stores.
    // Wave-local buffer: writes then same-wave reads; compiler orders via
    // lgkmcnt, so the 2-pass proj loop needs no extra barrier.
    short* ws = sm->st[wl];
#pragma unroll
    for (int t = 0; t < 4; t++) {
      int col = gy * 64 + t * 16 + m;
      float bs = bias[e * DIM + col];
#pragma unroll
      for (int r = 0; r < 4; r++)
        ws[(quad * 4 + r) * 72 + t * 16 + m] = f2bf(acc[t][r] + bs);
    }
    int rr = lane >> 2, cg2 = (lane & 3) * 16;
    s8 v0 = *(s8*)&ws[rr * 72 + cg2];
    s8 v1 = *(s8*)&ws[rr * 72 + cg2 + 8];
    short* dst = ((mtx == 1) ? pp.kg : pp.qg) +
                 (size_t)(row0 + wl * 16 + rr) * DIM + gy * 64 + cg2;
    *(s8*)dst = v0;
    *(s8*)(dst + 8) = v1;
  }
}

// ---------------------------------------------------------------------------
// Phase C: split-K MFMA flash attention (single-buffered K/V staging).
// Fixed-shift softmax -> additive partials; phase D combines.
// ---------------------------------------------------------------------------
static __device__ void phase_attn(const P& pp, SMem* sm, int u) {
  if (u >= NATTN) return;
  int b = u % MAXST;
  int h = (u / MAXST) % NHEAD;
  int sp = u / (MAXST * NHEAD);
  if (b >= *pp.nstp) return;
  int e = pp.st_e[b];
  int row0 = pp.st_row[b];
  int g0 = pp.gs[e], kend = pp.gep[e];
  int ntiles = (kend - g0 + 63) >> 6;
  int tpc = (ntiles + NSPLIT - 1) / NSPLIT;
  int t0i = sp * tpc;
  int t1i = min(ntiles, t0i + tpc);
  int start = g0 + t0i * 64, end = g0 + t1i * 64;

  int tid = threadIdx.x;
  int wl = tid >> 6, lane = tid & 63;
  int m = lane & 15, quad = lane >> 4;
  int r0 = tid >> 3;
  int c0 = (tid & 7) * 8;

  short* k_s = sm->at.k;
  short* v_s = sm->at.v;
  short* p_s = sm->at.p;

  f4 o_acc[4];
  float l_r[4];
#pragma unroll
  for (int t = 0; t < 4; t++) o_acc[t] = (f4){0.f, 0.f, 0.f, 0.f};
#pragma unroll
  for (int r = 0; r < 4; r++) l_r[r] = 0.f;

  if (start < end) {
    int qrow = row0 + wl * 16 + m;
    if (qrow >= kend) qrow = row0;
    s8 qf0 = *(const s8*)&pp.qg[(size_t)qrow * DIM + h * DPH + quad * 8];
    s8 qf1 = *(const s8*)&pp.qg[(size_t)qrow * DIM + h * DPH + 32 + quad * 8];

    s8 pk0, pk1, pv0, pv1;
#define PREF(JT)                                                               \
  do {                                                                         \
    pk0 = *(const s8*)&pp.kg[(size_t)((JT) + r0) * DIM + h * DPH + c0];        \
    pk1 = *(const s8*)&pp.kg[(size_t)((JT) + r0 + 32) * DIM + h * DPH + c0];   \
    pv0 = *(const s8*)&pp.vgT[(size_t)(h * DPH + r0) * VPITCH + (JT) + c0];    \
    pv1 =                                                                      \
        *(const s8*)&pp.vgT[(size_t)(h * DPH + r0 + 32) * VPITCH + (JT) + c0]; \
  } while (0)

    PREF(start);
    for (int jt = start; jt < end; jt += 64) {
      __syncthreads();  // prev tile's LDS readers done
      *(s8*)&k_s[r0 * 72 + c0] = pk0;
      *(s8*)&k_s[(r0 + 32) * 72 + c0] = pk1;
      *(s8*)&v_s[r0 * 72 + c0] = pv0;
      *(s8*)&v_s[(r0 + 32) * 72 + c0] = pv1;
      int jn = jt + 64;
      if (jn < end) PREF(jn);  // overlap next tile's loads with compute
      __syncthreads();

      f4 s_acc[4];
#pragma unroll
      for (int t = 0; t < 4; t++) s_acc[t] = (f4){0.f, 0.f, 0.f, 0.f};
#pragma unroll
      for (int t = 0; t < 4; t++) {
        s8 kb0 = *(s8*)&k_s[(t * 16 + m) * 72 + quad * 8];
        s8 kb1 = *(s8*)&k_s[(t * 16 + m) * 72 + 32 + quad * 8];
        s_acc[t] =
            __builtin_amdgcn_mfma_f32_16x16x32_bf16(qf0, kb0, s_acc[t], 0, 0, 0);
        s_acc[t] =
            __builtin_amdgcn_mfma_f32_16x16x32_bf16(qf1, kb1, s_acc[t], 0, 0, 0);
      }

      // p = exp(s*scale) (bounded scores -> shift-free exact), tail-masked.
#pragma unroll
      for (int t = 0; t < 4; t++) {
        bool ok = (jt + t * 16 + m) < kend;
#pragma unroll
        for (int r = 0; r < 4; r++) {
          float p = ok ? __expf(s_acc[t][r] * SCALE) : 0.f;
          l_r[r] += p;
          p_s[(wl * 16 + quad * 4 + r) * 72 + t * 16 + m] = f2bf(p);
        }
      }

#pragma unroll
      for (int kk = 0; kk < 2; kk++) {
        s8 pa = *(s8*)&p_s[(wl * 16 + m) * 72 + kk * 32 + quad * 8];
#pragma unroll
        for (int t = 0; t < 4; t++) {
          s8 vb = *(s8*)&v_s[(t * 16 + m) * 72 + kk * 32 + quad * 8];
          o_acc[t] =
              __builtin_amdgcn_mfma_f32_16x16x32_bf16(pa, vb, o_acc[t], 0, 0, 0);
        }
      }
    }
#undef PREF
  }

  // Epilogue: write UNNORMALIZED partial O (f32, coalesced 64B segments) +
  // partial l. Empty chunks write zeros so phase D never reads poisoned ws.
  float* Ob = pp.Op + (size_t)sp * GPAD * DIM;
#pragma unroll
  for (int r = 0; r < 4; r++) {
    float lt = l_r[r];
#pragma unroll
    for (int o = 8; o > 0; o >>= 1) lt += __shfl_xor(lt, o, 64);
    int grow = row0 + wl * 16 + quad * 4 + r;
    if (m == 0) pp.lp[(size_t)(sp * NHEAD + h) * GPAD + grow] = lt;
#pragma unroll
    for (int t = 0; t < 4; t++)
      Ob[(size_t)grow * DIM + h * DPH + t * 16 + m] = o_acc[t][r];
  }
}

// ---------------------------------------------------------------------------
// Phase D: combine splits + out-proj + LayerNorm. Unit = 16 tokens (token
// order). Each thread sums NSPLIT partials for its A-frag row, divides by
// summed l, converts to bf16 frags, then MFMA Wf GEMM + residual + LN.
// ---------------------------------------------------------------------------
static __device__ void phase_out(const P& pp, SMem* sm, int u) {
  if (u >= N_TOK / 16) return;
  int t0 = u * 16;
  int tid = threadIdx.x, wl = tid >> 6, lane = tid & 63;
  int m = lane & 15, quad = lane >> 4;
  float* h_s = sm->h;

  int grow = pp.iperm[t0 + m];
  float inv[NHEAD];
#pragma unroll
  for (int h = 0; h < NHEAD; h++) {
    float s = 0.f;
#pragma unroll
    for (int sp = 0; sp < NSPLIT; sp++)
      s += pp.lp[(size_t)(sp * NHEAD + h) * GPAD + grow];
    inv[h] = 1.f / s;
  }

  s8 af[8];
#pragma unroll
  for (int kc = 0; kc < 8; kc++) {
    f4 s0 = (f4){0.f, 0.f, 0.f, 0.f}, s1 = (f4){0.f, 0.f, 0.f, 0.f};
#pragma unroll
    for (int sp = 0; sp < NSPLIT; sp++) {
      const float* p =
          pp.Op + ((size_t)sp * GPAD + grow) * DIM + kc * 32 + quad * 8;
      s0 += *(const f4*)p;
      s1 += *(const f4*)(p + 4);
    }
    float iv = inv[kc >> 1];
#pragma unroll
    for (int j = 0; j < 4; j++) {
      af[kc][j] = f2bf(s0[j] * iv);
      af[kc][4 + j] = f2bf(s1[j] * iv);
    }
  }

  const short* Bp =
      pp.WbT + (size_t)27 * 65536 + (size_t)(wl * 64 + m) * 256 + quad * 8;
  f4 acc[4];
#pragma unroll
  for (int t = 0; t < 4; t++) acc[t] = (f4){0.f, 0.f, 0.f, 0.f};
#pragma unroll
  for (int kc = 0; kc < 8; kc++)
#pragma unroll
    for (int t = 0; t < 4; t++) {
      s8 wb = *(const s8*)(Bp + t * 16 * 256 + kc * 32);
      acc[t] = __builtin_amdgcn_mfma_f32_16x16x32_bf16(af[kc], wb, acc[t], 0, 0, 0);
    }

#pragma unroll
  for (int t = 0; t < 4; t++) {
    int col = wl * 64 + t * 16 + m;
    float bs = pp.bfv[col];
#pragma unroll
    for (int r = 0; r < 4; r++)
      h_s[(quad * 4 + r) * 260 + col] = acc[t][r] + bs;
  }
  __syncthreads();

#pragma unroll
  for (int rr = 0; rr < 4; rr++) {
    int row = wl * 4 + rr;
    float hv[4];
#pragma unroll
    for (int k2 = 0; k2 < 4; k2++)
      hv[k2] = h_s[row * 260 + lane + 64 * k2] +
               pp.x[(size_t)(t0 + row) * DIM + lane + 64 * k2];
    float mean = wave_sum(hv[0] + hv[1] + hv[2] + hv[3]) * (1.f / 256.f);
    float sq = 0.f;
#pragma unroll
    for (int k2 = 0; k2 < 4; k2++) {
      float dd = hv[k2] - mean;
      sq += dd * dd;
    }
    float rstd = rsqrtf(wave_sum(sq) * (1.f / 256.f) + 1e-5f);
#pragma unroll
    for (int k2 = 0; k2 < 4; k2++) {
      int c = lane + 64 * k2;
      pp.out[(size_t)(t0 + row) * DIM + c] =
          pp.gamma[c] * ((hv[k2] - mean) * rstd) + pp.beta[c];
    }
  }
}

// ---------------------------------------------------------------------------
// Fused kernel: 768 blocks x 256 thr, 3 blocks/CU co-resident by
// construction. 3 hand-rolled grid syncs replace 3 launch/drain boundaries.
// ---------------------------------------------------------------------------
__global__ __launch_bounds__(256, 3) void k_fused(P pp) {
  __shared__ SMem sm;
  int bid = blockIdx.x;
  phase_prep(pp, &sm, bid);
  grid_sync();
  phase_proj(pp, &sm, bid);
  if (bid + GRID_X < NPROJ) phase_proj(pp, &sm, bid + GRID_X);
  grid_sync();
  phase_attn(pp, &sm, bid);
  grid_sync();
  phase_out(pp, &sm, bid);
}

// ---------------------------------------------------------------------------
extern "C" void kernel_launch(void* const* d_in, const int* in_sizes, int n_in,
                              void* d_out, int out_size, void* d_ws,
                              size_t ws_size, hipStream_t stream) {
  P p;
  p.x = (const float*)d_in[0];
  p.label = (const int*)d_in[1];
  p.Wq = (const float*)d_in[2];
  p.bq = (const float*)d_in[3];
  p.Wk = (const float*)d_in[4];
  p.bk = (const float*)d_in[5];
  p.Wv = (const float*)d_in[6];
  p.bv = (const float*)d_in[7];
  p.Wf = (const float*)d_in[8];
  p.bfv = (const float*)d_in[9];
  p.gamma = (const float*)d_in[10];
  p.beta = (const float*)d_in[11];
  p.out = (float*)d_out;

  // Workspace (~25 MB of 256 MB) — layout unchanged from 4-kernel version.
  p.perm = (int*)d_ws;            // 4800 slot
  p.iperm = p.perm + 4800;        // 4096
  p.gs = p.iperm + 4096;          // 16
  p.gep = p.gs + 16;              // 16
  p.st_e = p.gep + 16;            // 128
  p.st_row = p.st_e + 128;        // 128
  p.nstp = p.st_row + 128;        // 8
  p.qg = (short*)((char*)d_ws + 65536);
  p.kg = p.qg + (size_t)GPAD * DIM;
  p.vgT = p.kg + (size_t)GPAD * DIM;
  p.WbT = p.vgT + (size_t)DIM * VPITCH;
  p.xb = p.WbT + (size_t)28 * 65536;
  p.Op = (float*)(p.xb + (size_t)N_TOK * DIM);  // [NSPLIT][GPAD][256] f32
  p.lp = p.Op + (size_t)NSPLIT * GPAD * DIM;    // [NSPLIT][4][GPAD] f32

  hipLaunchKernelGGL(k_fused, dim3(GRID_X), dim3(256), 0, stream, p);
}

// Round 3
// 423.015 us; speedup vs baseline: 1.5791x; 1.5791x over previous
//
#include <hip/hip_runtime.h>
#include <math.h>

#define N_TOK 4096
#define DIM 256
#define NHEAD 4
#define DPH 64
#define NEXP 9
#define SCALE 0.25f
#define MAXST 80    // 64-row supertiles: <= 64 + 9
#define GPAD 4736   // 64-aligned grouped rows upper bound
#define VPITCH 4736
#define NSPLIT 2    // key-range splits per (supertile, head)
#define GRID_X 1024 // 4 blocks/CU x 256 CUs; LDS cap is 5/CU so always resident
#define NPROJ 960   // MAXST*4*3 proj units (single pass)
#define NATTN 640   // MAXST*NHEAD*NSPLIT attn units (single pass)

typedef short s8 __attribute__((ext_vector_type(8)));
typedef short s4 __attribute__((ext_vector_type(4)));
typedef float f4 __attribute__((ext_vector_type(4)));

struct P {
  const float* x;
  const int* label;
  const float *Wq, *Wk, *Wv, *Wf;
  const float *bq, *bk, *bv;
  const float *bfv, *gamma, *beta;
  float* out;
  int *perm, *iperm, *gs, *gep, *st_e, *st_row, *nstp;
  short *qg, *kg, *vgT, *WbT, *xb;
  float *Op, *lp;
};

// One LDS arena, re-purposed per phase (each grid sync includes a block
// barrier, so reuse is safe). Max member = attn: 27648 B.
union SMem {
  struct { int cnt[4][NEXP]; int gsh[NEXP]; } b0;          // prep block 0
  short tile[64 * 68];                                     // prep transpose
  short st[4][16 * 72];                                    // proj store-transpose
  struct { short k[64 * 72]; short v[64 * 72]; short p[4 * 16 * 72]; } at;
  float h[16 * 260];                                       // out LN staging
};

// ---------------------------------------------------------------------------
// Grid barrier v2. R2's version polled with ACQUIRE agent loads -> one
// buffer_inv PER POLL ITERATION from ~767 waves = L2-invalidate storm
// (measured: 150us/barrier, FETCH_SIZE inflated 45MB). Fix: RELAXED polling
// (plain sc1 load of the coherence point, no cache ops) and pay wbL2/inv
// exactly once per barrier via explicit agent fences. Sense-reversing
// generation counter in device globals: zero-init at load, self-resetting
// across graph replays. The gen bump is a RELEASE store so the cnt reset is
// ordered before it at the coherence point.
// Deadlock-free: LDS 27648B caps residency at 5 blocks/CU; 1024 <= 5*256
// even under worst-case packing, so all blocks are co-resident.
// ---------------------------------------------------------------------------
__device__ unsigned g_cnt = 0;
__device__ unsigned g_gen = 0;

static __device__ __forceinline__ void grid_sync() {
  __syncthreads();
  if (threadIdx.x == 0) {
    __builtin_amdgcn_fence(__ATOMIC_RELEASE, "agent");  // wb L2 once
    unsigned gen =
        __hip_atomic_load(&g_gen, __ATOMIC_RELAXED, __HIP_MEMORY_SCOPE_AGENT);
    unsigned old = __hip_atomic_fetch_add(&g_cnt, 1u, __ATOMIC_RELAXED,
                                          __HIP_MEMORY_SCOPE_AGENT);
    if (old == GRID_X - 1) {
      __hip_atomic_store(&g_cnt, 0u, __ATOMIC_RELAXED,
                         __HIP_MEMORY_SCOPE_AGENT);
      __hip_atomic_store(&g_gen, gen + 1u, __ATOMIC_RELEASE,
                         __HIP_MEMORY_SCOPE_AGENT);
    } else {
      while (__hip_atomic_load(&g_gen, __ATOMIC_RELAXED,
                               __HIP_MEMORY_SCOPE_AGENT) == gen) {
        __builtin_amdgcn_s_sleep(8);
      }
    }
    __builtin_amdgcn_fence(__ATOMIC_ACQUIRE, "agent");  // inv once
  }
  __syncthreads();
}

static __device__ __forceinline__ short f2bf(float f) {
  union { float f; unsigned u; } v;
  v.f = f;
  unsigned r = (v.u + 0x7FFFu + ((v.u >> 16) & 1u)) >> 16;
  return (short)r;
}

static __device__ __forceinline__ float wave_sum(float v) {
#pragma unroll
  for (int o = 32; o > 0; o >>= 1) v += __shfl_xor(v, o, 64);
  return v;
}

// ---------------------------------------------------------------------------
// Phase A: prep. Unit 0: atomic-free bucketing (ballot histogram + rank
// scatter). Units 1..448: W fp32 [d][h] -> WbT bf16 [slab][h][d]. Units
// 449..512: x -> bf16 cast. Units 513..1023 idle.
// ---------------------------------------------------------------------------
static __device__ void phase_prep(const P& pp, SMem* sm, int b) {
  int tid = threadIdx.x;
  if (b == 0) {
    int wl = tid >> 6, lane = tid & 63;
    int lab[16];
#pragma unroll
    for (int i = 0; i < 16; i++) lab[i] = pp.label[wl * 1024 + i * 64 + lane];

    int cw[NEXP];
#pragma unroll
    for (int e = 0; e < NEXP; e++) cw[e] = 0;
#pragma unroll
    for (int i = 0; i < 16; i++)
#pragma unroll
      for (int e = 0; e < NEXP; e++)
        cw[e] += __popcll(__ballot(lab[i] == e));
    if (lane == 0)
#pragma unroll
      for (int e = 0; e < NEXP; e++) sm->b0.cnt[wl][e] = cw[e];
    __syncthreads();

    if (tid == 0) {
      int run = 0, ns = 0;
      for (int e = 0; e < NEXP; e++) {
        int tot = sm->b0.cnt[0][e] + sm->b0.cnt[1][e] + sm->b0.cnt[2][e] +
                  sm->b0.cnt[3][e];
        pp.gs[e] = run;
        sm->b0.gsh[e] = run;
        int end = run + tot;
        pp.gep[e] = end;
        for (int r = run; r < end; r += 64) {
          pp.st_e[ns] = e;
          pp.st_row[ns] = r;
          ns++;
        }
        run = (end + 63) & ~63;  // 64-align next group start
      }
      *pp.nstp = ns;
    }
    __syncthreads();

    int baseW[NEXP];
#pragma unroll
    for (int e = 0; e < NEXP; e++) {
      int bse = sm->b0.gsh[e];
      for (int w = 0; w < 4; w++)
        if (w < wl) bse += sm->b0.cnt[w][e];
      baseW[e] = bse;
    }
    int run2[NEXP];
#pragma unroll
    for (int e = 0; e < NEXP; e++) run2[e] = 0;
#pragma unroll
    for (int i = 0; i < 16; i++) {
      int t = wl * 1024 + i * 64 + lane;
      int lv = lab[i];
      unsigned long long below = (1ull << lane) - 1ull;
      int pos = 0;
#pragma unroll
      for (int e = 0; e < NEXP; e++) {
        unsigned long long mk = __ballot(lv == e);
        if (lv == e) pos = baseW[e] + run2[e] + __popcll(mk & below);
        run2[e] += __popcll(mk);
      }
      pp.perm[pos] = t;
      pp.iperm[t] = pos;
    }
  } else if (b <= 448) {
    // Weight transpose: slabs 0-8 Wq, 9-17 Wk, 18-26 Wv, 27 Wf; 16 tiles/slab.
    int vt = b - 1;
    int slab = vt >> 4;
    const float* src = (slab < 9)    ? pp.Wq + (size_t)slab * 65536
                       : (slab < 18) ? pp.Wk + (size_t)(slab - 9) * 65536
                       : (slab < 27) ? pp.Wv + (size_t)(slab - 18) * 65536
                                     : pp.Wf;
    int xy = vt & 15;
    int d0 = (xy >> 2) * 64, h0 = (xy & 3) * 64;
    int rl = tid >> 4;
    int hh = (tid & 15) * 4;
#pragma unroll
    for (int pq = 0; pq < 4; pq++) {
      int dl = pq * 16 + rl;
      float4 v = *(const float4*)(src + (size_t)(d0 + dl) * 256 + h0 + hh);
      s4 o;
      o[0] = f2bf(v.x); o[1] = f2bf(v.y); o[2] = f2bf(v.z); o[3] = f2bf(v.w);
      *(s4*)&sm->tile[dl * 68 + hh] = o;
    }
    __syncthreads();
    int hcol = tid >> 2, dq = (tid & 3) * 16;
    s8 pa, pb;
#pragma unroll
    for (int i = 0; i < 8; i++) {
      pa[i] = sm->tile[(dq + i) * 68 + hcol];
      pb[i] = sm->tile[(dq + 8 + i) * 68 + hcol];
    }
    short* dst =
        pp.WbT + (size_t)slab * 65536 + (size_t)(h0 + hcol) * 256 + d0 + dq;
    *(s8*)dst = pa;
    *(s8*)(dst + 8) = pb;
  } else if (b <= 512) {
    // x -> bf16, token order.
    int tok = (b - 449) * 64 + (tid >> 2);
    int qd = (tid & 3) * 64;
    const float* src = pp.x + (size_t)tok * DIM + qd;
    short* dst = pp.xb + (size_t)tok * DIM + qd;
#pragma unroll
    for (int i = 0; i < 16; i++) {
      float4 v = *(const float4*)(src + i * 4);
      s4 o;
      o[0] = f2bf(v.x); o[1] = f2bf(v.y); o[2] = f2bf(v.z); o[3] = f2bf(v.w);
      *(s4*)(dst + i * 4) = o;
    }
  }
}

// ---------------------------------------------------------------------------
// Phase B: MFMA QKV projection. Unit u -> (mtx, gy, supertile); wave = 16
// grouped rows x 64 cols; A-frags gathered via perm (clamped).
// ---------------------------------------------------------------------------
static __device__ void phase_proj(const P& pp, SMem* sm, int u) {
  int mtx = u / (MAXST * 4);
  int rem = u - mtx * (MAXST * 4);
  int gy = rem / MAXST;
  int bst = rem - gy * MAXST;
  if (bst >= *pp.nstp) return;
  int e = pp.st_e[bst];
  int row0 = pp.st_row[bst];
  int g1 = pp.gep[e];
  int tid = threadIdx.x, wl = tid >> 6, lane = tid & 63;
  int m = lane & 15, quad = lane >> 4;

  int row = row0 + wl * 16 + m;
  int pr = pp.perm[(row < g1) ? row : row0];  // clamp padding rows
  const short* Ap = pp.xb + (size_t)pr * DIM + quad * 8;
  const short* Bp = pp.WbT + (size_t)(mtx * 9 + e) * 65536 +
                    (size_t)(gy * 64 + m) * 256 + quad * 8;
  const float* bias = (mtx == 0) ? pp.bq : (mtx == 1) ? pp.bk : pp.bv;

  s8 ac = *(const s8*)Ap;
  s8 bc[4];
#pragma unroll
  for (int t = 0; t < 4; t++) bc[t] = *(const s8*)(Bp + t * 16 * 256);
  f4 acc[4];
#pragma unroll
  for (int t = 0; t < 4; t++) acc[t] = (f4){0.f, 0.f, 0.f, 0.f};
#pragma unroll
  for (int kc = 0; kc < 8; kc++) {
    s8 an = ac;
    s8 bn[4] = {bc[0], bc[1], bc[2], bc[3]};
    if (kc < 7) {
      an = *(const s8*)(Ap + (kc + 1) * 32);
#pragma unroll
      for (int t = 0; t < 4; t++)
        bn[t] = *(const s8*)(Bp + t * 16 * 256 + (kc + 1) * 32);
    }
#pragma unroll
    for (int t = 0; t < 4; t++)
      acc[t] = __builtin_amdgcn_mfma_f32_16x16x32_bf16(ac, bc[t], acc[t], 0, 0, 0);
    ac = an;
#pragma unroll
    for (int t = 0; t < 4; t++) bc[t] = bn[t];
  }

  if (mtx == 2) {
    // vgT[col][grow]: quad owns 4 consecutive grows per col -> 8B s4 stores.
#pragma unroll
    for (int t = 0; t < 4; t++) {
      int col = gy * 64 + t * 16 + m;
      float bs = bias[e * DIM + col];
      s4 o;
#pragma unroll
      for (int r = 0; r < 4; r++) o[r] = f2bf(acc[t][r] + bs);
      *(s4*)&pp.vgT[(size_t)col * VPITCH + row0 + wl * 16 + quad * 4] = o;
    }
  } else {
    // LDS transpose: C-layout -> [row][col] bf16, then coalesced stores.
    // Wave-local buffer: writes then same-wave reads; compiler orders via
    // lgkmcnt.
    short* ws = sm->st[wl];
#pragma unroll
    for (int t = 0; t < 4; t++) {
      int col = gy * 64 + t * 16 + m;
      float bs = bias[e * DIM + col];
#pragma unroll
      for (int r = 0; r < 4; r++)
        ws[(quad * 4 + r) * 72 + t * 16 + m] = f2bf(acc[t][r] + bs);
    }
    int rr = lane >> 2, cg2 = (lane & 3) * 16;
    s8 v0 = *(s8*)&ws[rr * 72 + cg2];
    s8 v1 = *(s8*)&ws[rr * 72 + cg2 + 8];
    short* dst = ((mtx == 1) ? pp.kg : pp.qg) +
                 (size_t)(row0 + wl * 16 + rr) * DIM + gy * 64 + cg2;
    *(s8*)dst = v0;
    *(s8*)(dst + 8) = v1;
  }
}

// ---------------------------------------------------------------------------
// Phase C: split-K MFMA flash attention (single-buffered K/V staging).
// Fixed-shift softmax -> additive partials; phase D combines.
// ---------------------------------------------------------------------------
static __device__ void phase_attn(const P& pp, SMem* sm, int u) {
  if (u >= NATTN) return;
  int b = u % MAXST;
  int h = (u / MAXST) % NHEAD;
  int sp = u / (MAXST * NHEAD);
  if (b >= *pp.nstp) return;
  int e = pp.st_e[b];
  int row0 = pp.st_row[b];
  int g0 = pp.gs[e], kend = pp.gep[e];
  int ntiles = (kend - g0 + 63) >> 6;
  int tpc = (ntiles + NSPLIT - 1) / NSPLIT;
  int t0i = sp * tpc;
  int t1i = min(ntiles, t0i + tpc);
  int start = g0 + t0i * 64, end = g0 + t1i * 64;

  int tid = threadIdx.x;
  int wl = tid >> 6, lane = tid & 63;
  int m = lane & 15, quad = lane >> 4;
  int r0 = tid >> 3;
  int c0 = (tid & 7) * 8;

  short* k_s = sm->at.k;
  short* v_s = sm->at.v;
  short* p_s = sm->at.p;

  f4 o_acc[4];
  float l_r[4];
#pragma unroll
  for (int t = 0; t < 4; t++) o_acc[t] = (f4){0.f, 0.f, 0.f, 0.f};
#pragma unroll
  for (int r = 0; r < 4; r++) l_r[r] = 0.f;

  if (start < end) {
    int qrow = row0 + wl * 16 + m;
    if (qrow >= kend) qrow = row0;
    s8 qf0 = *(const s8*)&pp.qg[(size_t)qrow * DIM + h * DPH + quad * 8];
    s8 qf1 = *(const s8*)&pp.qg[(size_t)qrow * DIM + h * DPH + 32 + quad * 8];

    s8 pk0, pk1, pv0, pv1;
#define PREF(JT)                                                               \
  do {                                                                         \
    pk0 = *(const s8*)&pp.kg[(size_t)((JT) + r0) * DIM + h * DPH + c0];        \
    pk1 = *(const s8*)&pp.kg[(size_t)((JT) + r0 + 32) * DIM + h * DPH + c0];   \
    pv0 = *(const s8*)&pp.vgT[(size_t)(h * DPH + r0) * VPITCH + (JT) + c0];    \
    pv1 =                                                                      \
        *(const s8*)&pp.vgT[(size_t)(h * DPH + r0 + 32) * VPITCH + (JT) + c0]; \
  } while (0)

    PREF(start);
    for (int jt = start; jt < end; jt += 64) {
      __syncthreads();  // prev tile's LDS readers done
      *(s8*)&k_s[r0 * 72 + c0] = pk0;
      *(s8*)&k_s[(r0 + 32) * 72 + c0] = pk1;
      *(s8*)&v_s[r0 * 72 + c0] = pv0;
      *(s8*)&v_s[(r0 + 32) * 72 + c0] = pv1;
      int jn = jt + 64;
      if (jn < end) PREF(jn);  // overlap next tile's loads with compute
      __syncthreads();

      f4 s_acc[4];
#pragma unroll
      for (int t = 0; t < 4; t++) s_acc[t] = (f4){0.f, 0.f, 0.f, 0.f};
#pragma unroll
      for (int t = 0; t < 4; t++) {
        s8 kb0 = *(s8*)&k_s[(t * 16 + m) * 72 + quad * 8];
        s8 kb1 = *(s8*)&k_s[(t * 16 + m) * 72 + 32 + quad * 8];
        s_acc[t] =
            __builtin_amdgcn_mfma_f32_16x16x32_bf16(qf0, kb0, s_acc[t], 0, 0, 0);
        s_acc[t] =
            __builtin_amdgcn_mfma_f32_16x16x32_bf16(qf1, kb1, s_acc[t], 0, 0, 0);
      }

      // p = exp(s*scale) (bounded scores -> shift-free exact), tail-masked.
#pragma unroll
      for (int t = 0; t < 4; t++) {
        bool ok = (jt + t * 16 + m) < kend;
#pragma unroll
        for (int r = 0; r < 4; r++) {
          float p = ok ? __expf(s_acc[t][r] * SCALE) : 0.f;
          l_r[r] += p;
          p_s[(wl * 16 + quad * 4 + r) * 72 + t * 16 + m] = f2bf(p);
        }
      }

#pragma unroll
      for (int kk = 0; kk < 2; kk++) {
        s8 pa = *(s8*)&p_s[(wl * 16 + m) * 72 + kk * 32 + quad * 8];
#pragma unroll
        for (int t = 0; t < 4; t++) {
          s8 vb = *(s8*)&v_s[(t * 16 + m) * 72 + kk * 32 + quad * 8];
          o_acc[t] =
              __builtin_amdgcn_mfma_f32_16x16x32_bf16(pa, vb, o_acc[t], 0, 0, 0);
        }
      }
    }
#undef PREF
  }

  // Epilogue: write UNNORMALIZED partial O (f32, coalesced 64B segments) +
  // partial l. Empty chunks write zeros so phase D never reads poisoned ws.
  float* Ob = pp.Op + (size_t)sp * GPAD * DIM;
#pragma unroll
  for (int r = 0; r < 4; r++) {
    float lt = l_r[r];
#pragma unroll
    for (int o = 8; o > 0; o >>= 1) lt += __shfl_xor(lt, o, 64);
    int grow = row0 + wl * 16 + quad * 4 + r;
    if (m == 0) pp.lp[(size_t)(sp * NHEAD + h) * GPAD + grow] = lt;
#pragma unroll
    for (int t = 0; t < 4; t++)
      Ob[(size_t)grow * DIM + h * DPH + t * 16 + m] = o_acc[t][r];
  }
}

// ---------------------------------------------------------------------------
// Phase D: combine splits + out-proj + LayerNorm. Unit = 16 tokens (token
// order). Each thread sums NSPLIT partials for its A-frag row, divides by
// summed l, converts to bf16 frags, then MFMA Wf GEMM + residual + LN.
// ---------------------------------------------------------------------------
static __device__ void phase_out(const P& pp, SMem* sm, int u) {
  if (u >= N_TOK / 16) return;
  int t0 = u * 16;
  int tid = threadIdx.x, wl = tid >> 6, lane = tid & 63;
  int m = lane & 15, quad = lane >> 4;
  float* h_s = sm->h;

  int grow = pp.iperm[t0 + m];
  float inv[NHEAD];
#pragma unroll
  for (int h = 0; h < NHEAD; h++) {
    float s = 0.f;
#pragma unroll
    for (int sp = 0; sp < NSPLIT; sp++)
      s += pp.lp[(size_t)(sp * NHEAD + h) * GPAD + grow];
    inv[h] = 1.f / s;
  }

  s8 af[8];
#pragma unroll
  for (int kc = 0; kc < 8; kc++) {
    f4 s0 = (f4){0.f, 0.f, 0.f, 0.f}, s1 = (f4){0.f, 0.f, 0.f, 0.f};
#pragma unroll
    for (int sp = 0; sp < NSPLIT; sp++) {
      const float* p =
          pp.Op + ((size_t)sp * GPAD + grow) * DIM + kc * 32 + quad * 8;
      s0 += *(const f4*)p;
      s1 += *(const f4*)(p + 4);
    }
    float iv = inv[kc >> 1];
#pragma unroll
    for (int j = 0; j < 4; j++) {
      af[kc][j] = f2bf(s0[j] * iv);
      af[kc][4 + j] = f2bf(s1[j] * iv);
    }
  }

  const short* Bp =
      pp.WbT + (size_t)27 * 65536 + (size_t)(wl * 64 + m) * 256 + quad * 8;
  f4 acc[4];
#pragma unroll
  for (int t = 0; t < 4; t++) acc[t] = (f4){0.f, 0.f, 0.f, 0.f};
#pragma unroll
  for (int kc = 0; kc < 8; kc++)
#pragma unroll
    for (int t = 0; t < 4; t++) {
      s8 wb = *(const s8*)(Bp + t * 16 * 256 + kc * 32);
      acc[t] = __builtin_amdgcn_mfma_f32_16x16x32_bf16(af[kc], wb, acc[t], 0, 0, 0);
    }

#pragma unroll
  for (int t = 0; t < 4; t++) {
    int col = wl * 64 + t * 16 + m;
    float bs = pp.bfv[col];
#pragma unroll
    for (int r = 0; r < 4; r++)
      h_s[(quad * 4 + r) * 260 + col] = acc[t][r] + bs;
  }
  __syncthreads();

#pragma unroll
  for (int rr = 0; rr < 4; rr++) {
    int row = wl * 4 + rr;
    float hv[4];
#pragma unroll
    for (int k2 = 0; k2 < 4; k2++)
      hv[k2] = h_s[row * 260 + lane + 64 * k2] +
               pp.x[(size_t)(t0 + row) * DIM + lane + 64 * k2];
    float mean = wave_sum(hv[0] + hv[1] + hv[2] + hv[3]) * (1.f / 256.f);
    float sq = 0.f;
#pragma unroll
    for (int k2 = 0; k2 < 4; k2++) {
      float dd = hv[k2] - mean;
      sq += dd * dd;
    }
    float rstd = rsqrtf(wave_sum(sq) * (1.f / 256.f) + 1e-5f);
#pragma unroll
    for (int k2 = 0; k2 < 4; k2++) {
      int c = lane + 64 * k2;
      pp.out[(size_t)(t0 + row) * DIM + c] =
          pp.gamma[c] * ((hv[k2] - mean) * rstd) + pp.beta[c];
    }
  }
}

// ---------------------------------------------------------------------------
// Fused kernel: 1024 blocks x 256 thr (4/CU avg, LDS-capped max 5/CU so all
// resident). 3 cheap grid syncs replace 3 launch/drain boundaries.
// ---------------------------------------------------------------------------
__global__ __launch_bounds__(256, 4) void k_fused(P pp) {
  __shared__ SMem sm;
  int bid = blockIdx.x;
  phase_prep(pp, &sm, bid);
  grid_sync();
  if (bid < NPROJ) phase_proj(pp, &sm, bid);
  grid_sync();
  phase_attn(pp, &sm, bid);
  grid_sync();
  phase_out(pp, &sm, bid);
}

// ---------------------------------------------------------------------------
extern "C" void kernel_launch(void* const* d_in, const int* in_sizes, int n_in,
                              void* d_out, int out_size, void* d_ws,
                              size_t ws_size, hipStream_t stream) {
  P p;
  p.x = (const float*)d_in[0];
  p.label = (const int*)d_in[1];
  p.Wq = (const float*)d_in[2];
  p.bq = (const float*)d_in[3];
  p.Wk = (const float*)d_in[4];
  p.bk = (const float*)d_in[5];
  p.Wv = (const float*)d_in[6];
  p.bv = (const float*)d_in[7];
  p.Wf = (const float*)d_in[8];
  p.bfv = (const float*)d_in[9];
  p.gamma = (const float*)d_in[10];
  p.beta = (const float*)d_in[11];
  p.out = (float*)d_out;

  // Workspace (~25 MB of 256 MB) — layout unchanged from 4-kernel version.
  p.perm = (int*)d_ws;            // 4800 slot
  p.iperm = p.perm + 4800;        // 4096
  p.gs = p.iperm + 4096;          // 16
  p.gep = p.gs + 16;              // 16
  p.st_e = p.gep + 16;            // 128
  p.st_row = p.st_e + 128;        // 128
  p.nstp = p.st_row + 128;        // 8
  p.qg = (short*)((char*)d_ws + 65536);
  p.kg = p.qg + (size_t)GPAD * DIM;
  p.vgT = p.kg + (size_t)GPAD * DIM;
  p.WbT = p.vgT + (size_t)DIM * VPITCH;
  p.xb = p.WbT + (size_t)28 * 65536;
  p.Op = (float*)(p.xb + (size_t)N_TOK * DIM);  // [NSPLIT][GPAD][256] f32
  p.lp = p.Op + (size_t)NSPLIT * GPAD * DIM;    // [NSPLIT][4][GPAD] f32

  hipLaunchKernelGGL(k_fused, dim3(GRID_X), dim3(256), 0, stream, p);
}

// Round 4
// 205.001 us; speedup vs baseline: 3.2585x; 2.0635x over previous
//
#include <hip/hip_runtime.h>
#include <math.h>

#define N_TOK 4096
#define DIM 256
#define NHEAD 4
#define DPH 64
#define NEXP 9
#define SCALE 0.25f
#define MAXST 80    // 64-row supertiles: <= 64 + 9
#define GPAD 4736   // 64-aligned grouped rows upper bound
#define VPITCH 4736
#define NSPLIT 2    // key-range splits per (supertile, head)
#define GRID_X 1024 // 4 blocks/CU x 256 CUs; LDS cap is 5/CU so always resident
#define NPROJ 960   // MAXST*4*3 proj units (single pass)
#define NATTN 640   // MAXST*NHEAD*NSPLIT attn units (single pass)

typedef short s8 __attribute__((ext_vector_type(8)));
typedef short s4 __attribute__((ext_vector_type(4)));
typedef float f4 __attribute__((ext_vector_type(4)));

struct P {
  const float* x;
  const int* label;
  const float *Wq, *Wk, *Wv, *Wf;
  const float *bq, *bk, *bv;
  const float *bfv, *gamma, *beta;
  float* out;
  int *perm, *iperm, *gs, *gep, *st_e, *st_row, *nstp;
  short *qg, *kg, *vgT, *WbT, *xb;
  float *Op, *lp;
};

// One LDS arena, re-purposed per phase (each grid sync includes a block
// barrier, so reuse is safe). Max member = attn: 27648 B.
union SMem {
  struct { int cnt[4][NEXP]; int gsh[NEXP]; } b0;          // prep block 0
  short tile[64 * 68];                                     // prep transpose
  short st[4][16 * 72];                                    // proj store-transpose
  struct { short k[64 * 72]; short v[64 * 72]; short p[4 * 16 * 72]; } at;
  float h[16 * 260];                                       // out LN staging
};

// ---------------------------------------------------------------------------
// Grid barrier v3. Lessons: R2's ACQUIRE-polling = buffer_inv per poll
// (608us). R3's once-per-barrier acquire fence still = 1024x full-L2
// buffer_inv per barrier -> every phase restarted cache-cold (356us,
// FETCH 48MB). v3 drops the acquire side ENTIRELY, justified by data-flow:
// every cross-phase buffer is single-writer-phase, read-only afterward.
// At kernel start caches are invalid (dispatch acquire); a reader XCD
// either holds its OWN written lines (newest) or misses to MALL, which is
// coherent after writers' release wbL2. CDNA L1 is write-through /
// no-write-allocate, so no partial-line staleness. => release-only barrier:
//   arrive: fence(release, agent)  [s_waitcnt + buffer_wbl2 sc1, once]
//           fetch_add relaxed on g_cnt (own 256B line)
//   last:   reset cnt, RELEASE-store gen+1 (orders reset before bump)
//   others: poll g_gen RELAXED (plain sc1 load, no cache ops), s_sleep(32)
// Counters on separate 256B-aligned lines: polls of g_gen no longer contend
// with arrival RMWs on g_cnt at the MALL atomic unit.
// Deadlock-free: LDS 27648B caps residency at 5 blocks/CU; 1024 <= 5*256,
// so all blocks co-resident. Zero-init at load; self-resetting across
// graph replays.
// ---------------------------------------------------------------------------
__device__ __attribute__((aligned(256))) unsigned g_cnt = 0;
__device__ __attribute__((aligned(256))) unsigned g_gen = 0;

static __device__ __forceinline__ void grid_sync() {
  __syncthreads();
  if (threadIdx.x == 0) {
    __builtin_amdgcn_fence(__ATOMIC_RELEASE, "agent");  // waitcnt + wbL2, once
    unsigned gen =
        __hip_atomic_load(&g_gen, __ATOMIC_RELAXED, __HIP_MEMORY_SCOPE_AGENT);
    unsigned old = __hip_atomic_fetch_add(&g_cnt, 1u, __ATOMIC_RELAXED,
                                          __HIP_MEMORY_SCOPE_AGENT);
    if (old == GRID_X - 1) {
      __hip_atomic_store(&g_cnt, 0u, __ATOMIC_RELAXED,
                         __HIP_MEMORY_SCOPE_AGENT);
      // RELEASE store: cnt reset ordered before gen bump at coherence point.
      __hip_atomic_store(&g_gen, gen + 1u, __ATOMIC_RELEASE,
                         __HIP_MEMORY_SCOPE_AGENT);
    } else {
      while (__hip_atomic_load(&g_gen, __ATOMIC_RELAXED,
                               __HIP_MEMORY_SCOPE_AGENT) == gen) {
        __builtin_amdgcn_s_sleep(32);
      }
    }
    // NO acquire fence: see data-flow justification above.
  }
  __syncthreads();
}

static __device__ __forceinline__ short f2bf(float f) {
  union { float f; unsigned u; } v;
  v.f = f;
  unsigned r = (v.u + 0x7FFFu + ((v.u >> 16) & 1u)) >> 16;
  return (short)r;
}

static __device__ __forceinline__ float wave_sum(float v) {
#pragma unroll
  for (int o = 32; o > 0; o >>= 1) v += __shfl_xor(v, o, 64);
  return v;
}

// ---------------------------------------------------------------------------
// Phase A: prep. Unit 0: atomic-free bucketing (ballot histogram + rank
// scatter). Units 1..448: W fp32 [d][h] -> WbT bf16 [slab][h][d]. Units
// 449..512: x -> bf16 cast. Units 513..1023 idle.
// ---------------------------------------------------------------------------
static __device__ void phase_prep(const P& pp, SMem* sm, int b) {
  int tid = threadIdx.x;
  if (b == 0) {
    int wl = tid >> 6, lane = tid & 63;
    int lab[16];
#pragma unroll
    for (int i = 0; i < 16; i++) lab[i] = pp.label[wl * 1024 + i * 64 + lane];

    int cw[NEXP];
#pragma unroll
    for (int e = 0; e < NEXP; e++) cw[e] = 0;
#pragma unroll
    for (int i = 0; i < 16; i++)
#pragma unroll
      for (int e = 0; e < NEXP; e++)
        cw[e] += __popcll(__ballot(lab[i] == e));
    if (lane == 0)
#pragma unroll
      for (int e = 0; e < NEXP; e++) sm->b0.cnt[wl][e] = cw[e];
    __syncthreads();

    if (tid == 0) {
      int run = 0, ns = 0;
      for (int e = 0; e < NEXP; e++) {
        int tot = sm->b0.cnt[0][e] + sm->b0.cnt[1][e] + sm->b0.cnt[2][e] +
                  sm->b0.cnt[3][e];
        pp.gs[e] = run;
        sm->b0.gsh[e] = run;
        int end = run + tot;
        pp.gep[e] = end;
        for (int r = run; r < end; r += 64) {
          pp.st_e[ns] = e;
          pp.st_row[ns] = r;
          ns++;
        }
        run = (end + 63) & ~63;  // 64-align next group start
      }
      *pp.nstp = ns;
    }
    __syncthreads();

    int baseW[NEXP];
#pragma unroll
    for (int e = 0; e < NEXP; e++) {
      int bse = sm->b0.gsh[e];
      for (int w = 0; w < 4; w++)
        if (w < wl) bse += sm->b0.cnt[w][e];
      baseW[e] = bse;
    }
    int run2[NEXP];
#pragma unroll
    for (int e = 0; e < NEXP; e++) run2[e] = 0;
#pragma unroll
    for (int i = 0; i < 16; i++) {
      int t = wl * 1024 + i * 64 + lane;
      int lv = lab[i];
      unsigned long long below = (1ull << lane) - 1ull;
      int pos = 0;
#pragma unroll
      for (int e = 0; e < NEXP; e++) {
        unsigned long long mk = __ballot(lv == e);
        if (lv == e) pos = baseW[e] + run2[e] + __popcll(mk & below);
        run2[e] += __popcll(mk);
      }
      pp.perm[pos] = t;
      pp.iperm[t] = pos;
    }
  } else if (b <= 448) {
    // Weight transpose: slabs 0-8 Wq, 9-17 Wk, 18-26 Wv, 27 Wf; 16 tiles/slab.
    int vt = b - 1;
    int slab = vt >> 4;
    const float* src = (slab < 9)    ? pp.Wq + (size_t)slab * 65536
                       : (slab < 18) ? pp.Wk + (size_t)(slab - 9) * 65536
                       : (slab < 27) ? pp.Wv + (size_t)(slab - 18) * 65536
                                     : pp.Wf;
    int xy = vt & 15;
    int d0 = (xy >> 2) * 64, h0 = (xy & 3) * 64;
    int rl = tid >> 4;
    int hh = (tid & 15) * 4;
#pragma unroll
    for (int pq = 0; pq < 4; pq++) {
      int dl = pq * 16 + rl;
      float4 v = *(const float4*)(src + (size_t)(d0 + dl) * 256 + h0 + hh);
      s4 o;
      o[0] = f2bf(v.x); o[1] = f2bf(v.y); o[2] = f2bf(v.z); o[3] = f2bf(v.w);
      *(s4*)&sm->tile[dl * 68 + hh] = o;
    }
    __syncthreads();
    int hcol = tid >> 2, dq = (tid & 3) * 16;
    s8 pa, pb;
#pragma unroll
    for (int i = 0; i < 8; i++) {
      pa[i] = sm->tile[(dq + i) * 68 + hcol];
      pb[i] = sm->tile[(dq + 8 + i) * 68 + hcol];
    }
    short* dst =
        pp.WbT + (size_t)slab * 65536 + (size_t)(h0 + hcol) * 256 + d0 + dq;
    *(s8*)dst = pa;
    *(s8*)(dst + 8) = pb;
  } else if (b <= 512) {
    // x -> bf16, token order.
    int tok = (b - 449) * 64 + (tid >> 2);
    int qd = (tid & 3) * 64;
    const float* src = pp.x + (size_t)tok * DIM + qd;
    short* dst = pp.xb + (size_t)tok * DIM + qd;
#pragma unroll
    for (int i = 0; i < 16; i++) {
      float4 v = *(const float4*)(src + i * 4);
      s4 o;
      o[0] = f2bf(v.x); o[1] = f2bf(v.y); o[2] = f2bf(v.z); o[3] = f2bf(v.w);
      *(s4*)(dst + i * 4) = o;
    }
  }
}

// ---------------------------------------------------------------------------
// Phase B: MFMA QKV projection. Unit u -> (mtx, gy, supertile); wave = 16
// grouped rows x 64 cols; A-frags gathered via perm (clamped).
// ---------------------------------------------------------------------------
static __device__ void phase_proj(const P& pp, SMem* sm, int u) {
  int mtx = u / (MAXST * 4);
  int rem = u - mtx * (MAXST * 4);
  int gy = rem / MAXST;
  int bst = rem - gy * MAXST;
  if (bst >= *pp.nstp) return;
  int e = pp.st_e[bst];
  int row0 = pp.st_row[bst];
  int g1 = pp.gep[e];
  int tid = threadIdx.x, wl = tid >> 6, lane = tid & 63;
  int m = lane & 15, quad = lane >> 4;

  int row = row0 + wl * 16 + m;
  int pr = pp.perm[(row < g1) ? row : row0];  // clamp padding rows
  const short* Ap = pp.xb + (size_t)pr * DIM + quad * 8;
  const short* Bp = pp.WbT + (size_t)(mtx * 9 + e) * 65536 +
                    (size_t)(gy * 64 + m) * 256 + quad * 8;
  const float* bias = (mtx == 0) ? pp.bq : (mtx == 1) ? pp.bk : pp.bv;

  s8 ac = *(const s8*)Ap;
  s8 bc[4];
#pragma unroll
  for (int t = 0; t < 4; t++) bc[t] = *(const s8*)(Bp + t * 16 * 256);
  f4 acc[4];
#pragma unroll
  for (int t = 0; t < 4; t++) acc[t] = (f4){0.f, 0.f, 0.f, 0.f};
#pragma unroll
  for (int kc = 0; kc < 8; kc++) {
    s8 an = ac;
    s8 bn[4] = {bc[0], bc[1], bc[2], bc[3]};
    if (kc < 7) {
      an = *(const s8*)(Ap + (kc + 1) * 32);
#pragma unroll
      for (int t = 0; t < 4; t++)
        bn[t] = *(const s8*)(Bp + t * 16 * 256 + (kc + 1) * 32);
    }
#pragma unroll
    for (int t = 0; t < 4; t++)
      acc[t] = __builtin_amdgcn_mfma_f32_16x16x32_bf16(ac, bc[t], acc[t], 0, 0, 0);
    ac = an;
#pragma unroll
    for (int t = 0; t < 4; t++) bc[t] = bn[t];
  }

  if (mtx == 2) {
    // vgT[col][grow]: quad owns 4 consecutive grows per col -> 8B s4 stores.
#pragma unroll
    for (int t = 0; t < 4; t++) {
      int col = gy * 64 + t * 16 + m;
      float bs = bias[e * DIM + col];
      s4 o;
#pragma unroll
      for (int r = 0; r < 4; r++) o[r] = f2bf(acc[t][r] + bs);
      *(s4*)&pp.vgT[(size_t)col * VPITCH + row0 + wl * 16 + quad * 4] = o;
    }
  } else {
    // LDS transpose: C-layout -> [row][col] bf16, then coalesced stores.
    // Wave-local buffer: writes then same-wave reads; compiler orders via
    // lgkmcnt.
    short* ws = sm->st[wl];
#pragma unroll
    for (int t = 0; t < 4; t++) {
      int col = gy * 64 + t * 16 + m;
      float bs = bias[e * DIM + col];
#pragma unroll
      for (int r = 0; r < 4; r++)
        ws[(quad * 4 + r) * 72 + t * 16 + m] = f2bf(acc[t][r] + bs);
    }
    int rr = lane >> 2, cg2 = (lane & 3) * 16;
    s8 v0 = *(s8*)&ws[rr * 72 + cg2];
    s8 v1 = *(s8*)&ws[rr * 72 + cg2 + 8];
    short* dst = ((mtx == 1) ? pp.kg : pp.qg) +
                 (size_t)(row0 + wl * 16 + rr) * DIM + gy * 64 + cg2;
    *(s8*)dst = v0;
    *(s8*)(dst + 8) = v1;
  }
}

// ---------------------------------------------------------------------------
// Phase C: split-K MFMA flash attention (single-buffered K/V staging).
// Fixed-shift softmax -> additive partials; phase D combines.
// ---------------------------------------------------------------------------
static __device__ void phase_attn(const P& pp, SMem* sm, int u) {
  if (u >= NATTN) return;
  int b = u % MAXST;
  int h = (u / MAXST) % NHEAD;
  int sp = u / (MAXST * NHEAD);
  if (b >= *pp.nstp) return;
  int e = pp.st_e[b];
  int row0 = pp.st_row[b];
  int g0 = pp.gs[e], kend = pp.gep[e];
  int ntiles = (kend - g0 + 63) >> 6;
  int tpc = (ntiles + NSPLIT - 1) / NSPLIT;
  int t0i = sp * tpc;
  int t1i = min(ntiles, t0i + tpc);
  int start = g0 + t0i * 64, end = g0 + t1i * 64;

  int tid = threadIdx.x;
  int wl = tid >> 6, lane = tid & 63;
  int m = lane & 15, quad = lane >> 4;
  int r0 = tid >> 3;
  int c0 = (tid & 7) * 8;

  short* k_s = sm->at.k;
  short* v_s = sm->at.v;
  short* p_s = sm->at.p;

  f4 o_acc[4];
  float l_r[4];
#pragma unroll
  for (int t = 0; t < 4; t++) o_acc[t] = (f4){0.f, 0.f, 0.f, 0.f};
#pragma unroll
  for (int r = 0; r < 4; r++) l_r[r] = 0.f;

  if (start < end) {
    int qrow = row0 + wl * 16 + m;
    if (qrow >= kend) qrow = row0;
    s8 qf0 = *(const s8*)&pp.qg[(size_t)qrow * DIM + h * DPH + quad * 8];
    s8 qf1 = *(const s8*)&pp.qg[(size_t)qrow * DIM + h * DPH + 32 + quad * 8];

    s8 pk0, pk1, pv0, pv1;
#define PREF(JT)                                                               \
  do {                                                                         \
    pk0 = *(const s8*)&pp.kg[(size_t)((JT) + r0) * DIM + h * DPH + c0];        \
    pk1 = *(const s8*)&pp.kg[(size_t)((JT) + r0 + 32) * DIM + h * DPH + c0];   \
    pv0 = *(const s8*)&pp.vgT[(size_t)(h * DPH + r0) * VPITCH + (JT) + c0];    \
    pv1 =                                                                      \
        *(const s8*)&pp.vgT[(size_t)(h * DPH + r0 + 32) * VPITCH + (JT) + c0]; \
  } while (0)

    PREF(start);
    for (int jt = start; jt < end; jt += 64) {
      __syncthreads();  // prev tile's LDS readers done
      *(s8*)&k_s[r0 * 72 + c0] = pk0;
      *(s8*)&k_s[(r0 + 32) * 72 + c0] = pk1;
      *(s8*)&v_s[r0 * 72 + c0] = pv0;
      *(s8*)&v_s[(r0 + 32) * 72 + c0] = pv1;
      int jn = jt + 64;
      if (jn < end) PREF(jn);  // overlap next tile's loads with compute
      __syncthreads();

      f4 s_acc[4];
#pragma unroll
      for (int t = 0; t < 4; t++) s_acc[t] = (f4){0.f, 0.f, 0.f, 0.f};
#pragma unroll
      for (int t = 0; t < 4; t++) {
        s8 kb0 = *(s8*)&k_s[(t * 16 + m) * 72 + quad * 8];
        s8 kb1 = *(s8*)&k_s[(t * 16 + m) * 72 + 32 + quad * 8];
        s_acc[t] =
            __builtin_amdgcn_mfma_f32_16x16x32_bf16(qf0, kb0, s_acc[t], 0, 0, 0);
        s_acc[t] =
            __builtin_amdgcn_mfma_f32_16x16x32_bf16(qf1, kb1, s_acc[t], 0, 0, 0);
      }

      // p = exp(s*scale) (bounded scores -> shift-free exact), tail-masked.
#pragma unroll
      for (int t = 0; t < 4; t++) {
        bool ok = (jt + t * 16 + m) < kend;
#pragma unroll
        for (int r = 0; r < 4; r++) {
          float p = ok ? __expf(s_acc[t][r] * SCALE) : 0.f;
          l_r[r] += p;
          p_s[(wl * 16 + quad * 4 + r) * 72 + t * 16 + m] = f2bf(p);
        }
      }

#pragma unroll
      for (int kk = 0; kk < 2; kk++) {
        s8 pa = *(s8*)&p_s[(wl * 16 + m) * 72 + kk * 32 + quad * 8];
#pragma unroll
        for (int t = 0; t < 4; t++) {
          s8 vb = *(s8*)&v_s[(t * 16 + m) * 72 + kk * 32 + quad * 8];
          o_acc[t] =
              __builtin_amdgcn_mfma_f32_16x16x32_bf16(pa, vb, o_acc[t], 0, 0, 0);
        }
      }
    }
#undef PREF
  }

  // Epilogue: write UNNORMALIZED partial O (f32, coalesced 64B segments) +
  // partial l. Empty chunks write zeros so phase D never reads poisoned ws.
  float* Ob = pp.Op + (size_t)sp * GPAD * DIM;
#pragma unroll
  for (int r = 0; r < 4; r++) {
    float lt = l_r[r];
#pragma unroll
    for (int o = 8; o > 0; o >>= 1) lt += __shfl_xor(lt, o, 64);
    int grow = row0 + wl * 16 + quad * 4 + r;
    if (m == 0) pp.lp[(size_t)(sp * NHEAD + h) * GPAD + grow] = lt;
#pragma unroll
    for (int t = 0; t < 4; t++)
      Ob[(size_t)grow * DIM + h * DPH + t * 16 + m] = o_acc[t][r];
  }
}

// ---------------------------------------------------------------------------
// Phase D: combine splits + out-proj + LayerNorm. Unit = 16 tokens (token
// order). Each thread sums NSPLIT partials for its A-frag row, divides by
// summed l, converts to bf16 frags, then MFMA Wf GEMM + residual + LN.
// ---------------------------------------------------------------------------
static __device__ void phase_out(const P& pp, SMem* sm, int u) {
  if (u >= N_TOK / 16) return;
  int t0 = u * 16;
  int tid = threadIdx.x, wl = tid >> 6, lane = tid & 63;
  int m = lane & 15, quad = lane >> 4;
  float* h_s = sm->h;

  int grow = pp.iperm[t0 + m];
  float inv[NHEAD];
#pragma unroll
  for (int h = 0; h < NHEAD; h++) {
    float s = 0.f;
#pragma unroll
    for (int sp = 0; sp < NSPLIT; sp++)
      s += pp.lp[(size_t)(sp * NHEAD + h) * GPAD + grow];
    inv[h] = 1.f / s;
  }

  s8 af[8];
#pragma unroll
  for (int kc = 0; kc < 8; kc++) {
    f4 s0 = (f4){0.f, 0.f, 0.f, 0.f}, s1 = (f4){0.f, 0.f, 0.f, 0.f};
#pragma unroll
    for (int sp = 0; sp < NSPLIT; sp++) {
      const float* p =
          pp.Op + ((size_t)sp * GPAD + grow) * DIM + kc * 32 + quad * 8;
      s0 += *(const f4*)p;
      s1 += *(const f4*)(p + 4);
    }
    float iv = inv[kc >> 1];
#pragma unroll
    for (int j = 0; j < 4; j++) {
      af[kc][j] = f2bf(s0[j] * iv);
      af[kc][4 + j] = f2bf(s1[j] * iv);
    }
  }

  const short* Bp =
      pp.WbT + (size_t)27 * 65536 + (size_t)(wl * 64 + m) * 256 + quad * 8;
  f4 acc[4];
#pragma unroll
  for (int t = 0; t < 4; t++) acc[t] = (f4){0.f, 0.f, 0.f, 0.f};
#pragma unroll
  for (int kc = 0; kc < 8; kc++)
#pragma unroll
    for (int t = 0; t < 4; t++) {
      s8 wb = *(const s8*)(Bp + t * 16 * 256 + kc * 32);
      acc[t] = __builtin_amdgcn_mfma_f32_16x16x32_bf16(af[kc], wb, acc[t], 0, 0, 0);
    }

#pragma unroll
  for (int t = 0; t < 4; t++) {
    int col = wl * 64 + t * 16 + m;
    float bs = pp.bfv[col];
#pragma unroll
    for (int r = 0; r < 4; r++)
      h_s[(quad * 4 + r) * 260 + col] = acc[t][r] + bs;
  }
  __syncthreads();

#pragma unroll
  for (int rr = 0; rr < 4; rr++) {
    int row = wl * 4 + rr;
    float hv[4];
#pragma unroll
    for (int k2 = 0; k2 < 4; k2++)
      hv[k2] = h_s[row * 260 + lane + 64 * k2] +
               pp.x[(size_t)(t0 + row) * DIM + lane + 64 * k2];
    float mean = wave_sum(hv[0] + hv[1] + hv[2] + hv[3]) * (1.f / 256.f);
    float sq = 0.f;
#pragma unroll
    for (int k2 = 0; k2 < 4; k2++) {
      float dd = hv[k2] - mean;
      sq += dd * dd;
    }
    float rstd = rsqrtf(wave_sum(sq) * (1.f / 256.f) + 1e-5f);
#pragma unroll
    for (int k2 = 0; k2 < 4; k2++) {
      int c = lane + 64 * k2;
      pp.out[(size_t)(t0 + row) * DIM + c] =
          pp.gamma[c] * ((hv[k2] - mean) * rstd) + pp.beta[c];
    }
  }
}

// ---------------------------------------------------------------------------
// Fused kernel: 1024 blocks x 256 thr (4/CU avg, LDS-capped max 5/CU so all
// resident). 3 release-only grid syncs replace 3 launch/drain boundaries.
// ---------------------------------------------------------------------------
__global__ __launch_bounds__(256, 4) void k_fused(P pp) {
  __shared__ SMem sm;
  int bid = blockIdx.x;
  phase_prep(pp, &sm, bid);
  grid_sync();
  if (bid < NPROJ) phase_proj(pp, &sm, bid);
  grid_sync();
  phase_attn(pp, &sm, bid);
  grid_sync();
  phase_out(pp, &sm, bid);
}

// ---------------------------------------------------------------------------
extern "C" void kernel_launch(void* const* d_in, const int* in_sizes, int n_in,
                              void* d_out, int out_size, void* d_ws,
                              size_t ws_size, hipStream_t stream) {
  P p;
  p.x = (const float*)d_in[0];
  p.label = (const int*)d_in[1];
  p.Wq = (const float*)d_in[2];
  p.bq = (const float*)d_in[3];
  p.Wk = (const float*)d_in[4];
  p.bk = (const float*)d_in[5];
  p.Wv = (const float*)d_in[6];
  p.bv = (const float*)d_in[7];
  p.Wf = (const float*)d_in[8];
  p.bfv = (const float*)d_in[9];
  p.gamma = (const float*)d_in[10];
  p.beta = (const float*)d_in[11];
  p.out = (float*)d_out;

  // Workspace (~25 MB of 256 MB) — layout unchanged from 4-kernel version.
  p.perm = (int*)d_ws;            // 4800 slot
  p.iperm = p.perm + 4800;        // 4096
  p.gs = p.iperm + 4096;          // 16
  p.gep = p.gs + 16;              // 16
  p.st_e = p.gep + 16;            // 128
  p.st_row = p.st_e + 128;        // 128
  p.nstp = p.st_row + 128;        // 8
  p.qg = (short*)((char*)d_ws + 65536);
  p.kg = p.qg + (size_t)GPAD * DIM;
  p.vgT = p.kg + (size_t)GPAD * DIM;
  p.WbT = p.vgT + (size_t)DIM * VPITCH;
  p.xb = p.WbT + (size_t)28 * 65536;
  p.Op = (float*)(p.xb + (size_t)N_TOK * DIM);  // [NSPLIT][GPAD][256] f32
  p.lp = p.Op + (size_t)NSPLIT * GPAD * DIM;    // [NSPLIT][4][GPAD] f32

  hipLaunchKernelGGL(k_fused, dim3(GRID_X), dim3(256), 0, stream, p);
}

// Round 5
// 147.424 us; speedup vs baseline: 4.5311x; 1.3906x over previous
//
#include <hip/hip_runtime.h>
#include <math.h>

#define N_TOK 4096
#define DIM 256
#define NHEAD 4
#define DPH 64
#define NEXP 9
#define SCALE 0.25f
#define MAXST 80    // 64-row supertiles: <= 64 + 9
#define GPAD 4736   // 64-aligned grouped rows upper bound
#define VPITCH 4736
#define NSPLIT 4    // key-range splits per (supertile, head); R5: 2->4 for TLP

typedef short s8 __attribute__((ext_vector_type(8)));
typedef short s4 __attribute__((ext_vector_type(4)));
typedef float f4 __attribute__((ext_vector_type(4)));

static __device__ __forceinline__ short f2bf(float f) {
  union { float f; unsigned u; } v;
  v.f = f;
  unsigned r = (v.u + 0x7FFFu + ((v.u >> 16) & 1u)) >> 16;
  return (short)r;
}

static __device__ __forceinline__ float wave_sum(float v) {
#pragma unroll
  for (int o = 32; o > 0; o >>= 1) v += __shfl_xor(v, o, 64);
  return v;
}

// ---------------------------------------------------------------------------
// Kernel 1: prep. Block 0: bucket tokens — ATOMIC-FREE build: per-wave ballot
// histogram (wave-uniform register counts), LDS cross-wave prefix, then
// deterministic rank scatter. Blocks 1..448: W fp32 [d][h] -> WbT bf16
// [slab][h][d]. Blocks 449..512: x -> bf16 cast.
// ---------------------------------------------------------------------------
__global__ __launch_bounds__(256) void k_prep(
    const float* __restrict__ x, const int* __restrict__ label,
    const float* __restrict__ Wq, const float* __restrict__ Wk,
    const float* __restrict__ Wv, const float* __restrict__ Wf,
    int* __restrict__ perm, int* __restrict__ iperm, int* __restrict__ gs,
    int* __restrict__ gep, int* __restrict__ st_e, int* __restrict__ st_row,
    int* __restrict__ nstp, short* __restrict__ WbT, short* __restrict__ xb) {
  int b = blockIdx.x;
  int tid = threadIdx.x;
  if (b == 0) {
    __shared__ int cnt_s[4][NEXP];  // per-wave counts
    __shared__ int gsh[NEXP];       // group starts (LDS copy)
    int wl = tid >> 6, lane = tid & 63;
    int lab[16];
#pragma unroll
    for (int i = 0; i < 16; i++) lab[i] = label[wl * 1024 + i * 64 + lane];

    // Count: ballot popcount, accumulated in wave-uniform registers.
    int cw[NEXP];
#pragma unroll
    for (int e = 0; e < NEXP; e++) cw[e] = 0;
#pragma unroll
    for (int i = 0; i < 16; i++)
#pragma unroll
      for (int e = 0; e < NEXP; e++)
        cw[e] += __popcll(__ballot(lab[i] == e));
    if (lane == 0)
#pragma unroll
      for (int e = 0; e < NEXP; e++) cnt_s[wl][e] = cw[e];
    __syncthreads();

    if (tid == 0) {
      int run = 0, ns = 0;
      for (int e = 0; e < NEXP; e++) {
        int tot = cnt_s[0][e] + cnt_s[1][e] + cnt_s[2][e] + cnt_s[3][e];
        gs[e] = run;
        gsh[e] = run;
        int end = run + tot;
        gep[e] = end;
        for (int r = run; r < end; r += 64) {
          st_e[ns] = e;
          st_row[ns] = r;
          ns++;
        }
        run = (end + 63) & ~63;  // 64-align next group start
      }
      *nstp = ns;
    }
    __syncthreads();

    // Per-wave base = group start + counts of lower waves.
    int baseW[NEXP];
#pragma unroll
    for (int e = 0; e < NEXP; e++) {
      int bse = gsh[e];
      for (int w = 0; w < 4; w++)
        if (w < wl) bse += cnt_s[w][e];
      baseW[e] = bse;
    }
    // Scatter: deterministic rank, zero atomics.
    int run2[NEXP];
#pragma unroll
    for (int e = 0; e < NEXP; e++) run2[e] = 0;
#pragma unroll
    for (int i = 0; i < 16; i++) {
      int t = wl * 1024 + i * 64 + lane;
      int lv = lab[i];
      unsigned long long below = (1ull << lane) - 1ull;
      int pos = 0;
#pragma unroll
      for (int e = 0; e < NEXP; e++) {
        unsigned long long mk = __ballot(lv == e);
        if (lv == e) pos = baseW[e] + run2[e] + __popcll(mk & below);
        run2[e] += __popcll(mk);
      }
      perm[pos] = t;
      iperm[t] = pos;
    }
  } else if (b <= 448) {
    // Weight transpose: slabs 0-8 Wq, 9-17 Wk, 18-26 Wv, 27 Wf; 16 tiles/slab.
    __shared__ short tile[64 * 68];
    int vt = b - 1;
    int slab = vt >> 4;
    const float* src = (slab < 9)    ? Wq + (size_t)slab * 65536
                       : (slab < 18) ? Wk + (size_t)(slab - 9) * 65536
                       : (slab < 27) ? Wv + (size_t)(slab - 18) * 65536
                                     : Wf;
    int xy = vt & 15;
    int d0 = (xy >> 2) * 64, h0 = (xy & 3) * 64;
    int rl = tid >> 4;
    int hh = (tid & 15) * 4;
#pragma unroll
    for (int p = 0; p < 4; p++) {
      int dl = p * 16 + rl;
      float4 v = *(const float4*)(src + (size_t)(d0 + dl) * 256 + h0 + hh);
      s4 o;
      o[0] = f2bf(v.x); o[1] = f2bf(v.y); o[2] = f2bf(v.z); o[3] = f2bf(v.w);
      *(s4*)&tile[dl * 68 + hh] = o;
    }
    __syncthreads();
    int h = tid >> 2, dq = (tid & 3) * 16;
    s8 pa, pb;
#pragma unroll
    for (int i = 0; i < 8; i++) {
      pa[i] = tile[(dq + i) * 68 + h];
      pb[i] = tile[(dq + 8 + i) * 68 + h];
    }
    short* dst = WbT + (size_t)slab * 65536 + (size_t)(h0 + h) * 256 + d0 + dq;
    *(s8*)dst = pa;
    *(s8*)(dst + 8) = pb;
  } else {
    // x -> bf16, token order.
    int tok = (b - 449) * 64 + (tid >> 2);
    int qd = (tid & 3) * 64;
    const float* src = x + (size_t)tok * DIM + qd;
    short* dst = xb + (size_t)tok * DIM + qd;
#pragma unroll
    for (int i = 0; i < 16; i++) {
      float4 v = *(const float4*)(src + i * 4);
      s4 o;
      o[0] = f2bf(v.x); o[1] = f2bf(v.y); o[2] = f2bf(v.z); o[3] = f2bf(v.w);
      *(s4*)(dst + i * 4) = o;
    }
  }
}

// ---------------------------------------------------------------------------
// Kernel 2: MFMA QKV projection. Grid (supertile, colblock 0..3, mtx 0..2);
// wave = 16 grouped rows x 64 cols; A-frags gathered via perm (clamped).
// Epilogue: qg/kg via per-wave LDS transpose -> coalesced 16B stores;
// vgT via contiguous 8B s4 stores.
// ---------------------------------------------------------------------------
__global__ __launch_bounds__(256) void k_proj(
    const short* __restrict__ xb, const short* __restrict__ WbT,
    const float* __restrict__ bq, const float* __restrict__ bk,
    const float* __restrict__ bv, const int* __restrict__ perm,
    const int* __restrict__ gep, const int* __restrict__ st_e,
    const int* __restrict__ st_row, const int* __restrict__ nstp,
    short* __restrict__ qg, short* __restrict__ kg, short* __restrict__ vgT) {
  int b = blockIdx.x;
  if (b >= *nstp) return;
  int gy = blockIdx.y;
  int mtx = blockIdx.z;
  int e = st_e[b];
  int row0 = st_row[b];
  int g1 = gep[e];
  int tid = threadIdx.x, wl = tid >> 6, lane = tid & 63;
  int m = lane & 15, quad = lane >> 4;

  __shared__ short st_s[4][16 * 72];  // per-wave store-transpose buffer

  int row = row0 + wl * 16 + m;
  int pr = perm[(row < g1) ? row : row0];  // clamp padding rows
  const short* Ap = xb + (size_t)pr * DIM + quad * 8;
  const short* Bp = WbT + (size_t)(mtx * 9 + e) * 65536 +
                    (size_t)(gy * 64 + m) * 256 + quad * 8;
  const float* bias = (mtx == 0) ? bq : (mtx == 1) ? bk : bv;

  s8 ac = *(const s8*)Ap;
  s8 bc[4];
#pragma unroll
  for (int t = 0; t < 4; t++) bc[t] = *(const s8*)(Bp + t * 16 * 256);
  f4 acc[4];
#pragma unroll
  for (int t = 0; t < 4; t++) acc[t] = (f4){0.f, 0.f, 0.f, 0.f};
#pragma unroll
  for (int kc = 0; kc < 8; kc++) {
    s8 an = ac;
    s8 bn[4] = {bc[0], bc[1], bc[2], bc[3]};
    if (kc < 7) {
      an = *(const s8*)(Ap + (kc + 1) * 32);
#pragma unroll
      for (int t = 0; t < 4; t++)
        bn[t] = *(const s8*)(Bp + t * 16 * 256 + (kc + 1) * 32);
    }
#pragma unroll
    for (int t = 0; t < 4; t++)
      acc[t] = __builtin_amdgcn_mfma_f32_16x16x32_bf16(ac, bc[t], acc[t], 0, 0, 0);
    ac = an;
#pragma unroll
    for (int t = 0; t < 4; t++) bc[t] = bn[t];
  }

  if (mtx == 2) {
    // vgT[col][grow]: quad owns 4 consecutive grows per col -> 8B s4 stores.
#pragma unroll
    for (int t = 0; t < 4; t++) {
      int col = gy * 64 + t * 16 + m;
      float bs = bias[e * DIM + col];
      s4 o;
#pragma unroll
      for (int r = 0; r < 4; r++) o[r] = f2bf(acc[t][r] + bs);
      *(s4*)&vgT[(size_t)col * VPITCH + row0 + wl * 16 + quad * 4] = o;
    }
  } else {
    // LDS transpose: C-layout -> [row][col] bf16, then coalesced stores.
    short* ws = st_s[wl];
#pragma unroll
    for (int t = 0; t < 4; t++) {
      int col = gy * 64 + t * 16 + m;
      float bs = bias[e * DIM + col];
#pragma unroll
      for (int r = 0; r < 4; r++)
        ws[(quad * 4 + r) * 72 + t * 16 + m] = f2bf(acc[t][r] + bs);
    }
    // same-wave LDS ordering (compiler inserts lgkmcnt)
    int rr = lane >> 2, cg2 = (lane & 3) * 16;
    s8 v0 = *(s8*)&ws[rr * 72 + cg2];
    s8 v1 = *(s8*)&ws[rr * 72 + cg2 + 8];
    short* dst = ((mtx == 1) ? kg : qg) +
                 (size_t)(row0 + wl * 16 + rr) * DIM + gy * 64 + cg2;
    *(s8*)dst = v0;
    *(s8*)(dst + 8) = v1;
  }
}

// ---------------------------------------------------------------------------
// Kernel 3: split-K MFMA flash attention (single-buffered K/V staging).
// Fixed-shift softmax -> additive partials; k_out combines. NSPLIT=4:
// 1280 blocks = 5/CU (the LDS residency cap) for latency hiding; empty
// chunks write zero partials. Op/lp written NON-TEMPORAL: single-producer,
// single-consumer (k_out, cross-XCD) stream — no L2 allocate, smaller
// end-of-kernel writeback set.
// ---------------------------------------------------------------------------
__global__ __launch_bounds__(256) void k_attn(
    const short* __restrict__ qg, const short* __restrict__ kg,
    const short* __restrict__ vgT, const int* __restrict__ gs,
    const int* __restrict__ gep, const int* __restrict__ st_e,
    const int* __restrict__ st_row, const int* __restrict__ nstp,
    float* __restrict__ Op, float* __restrict__ lp) {
  int b = blockIdx.x;
  if (b >= *nstp) return;
  int h = blockIdx.y;
  int sp = blockIdx.z;
  int e = st_e[b];
  int row0 = st_row[b];
  int g0 = gs[e], kend = gep[e];
  int ntiles = (kend - g0 + 63) >> 6;
  int tpc = (ntiles + NSPLIT - 1) / NSPLIT;
  int t0i = sp * tpc;
  int t1i = min(ntiles, t0i + tpc);
  int start = g0 + t0i * 64, end = g0 + t1i * 64;

  int tid = threadIdx.x;
  int wl = tid >> 6, lane = tid & 63;
  int m = lane & 15, quad = lane >> 4;
  int r0 = tid >> 3;
  int c0 = (tid & 7) * 8;

  __shared__ short k_s[64 * 72];      // [key][dph]
  __shared__ short v_s[64 * 72];      // [dph][key] (transposed)
  __shared__ short p_s[4 * 16 * 72];  // per-wave [qrow][key]

  f4 o_acc[4];
  float l_r[4];
#pragma unroll
  for (int t = 0; t < 4; t++) o_acc[t] = (f4){0.f, 0.f, 0.f, 0.f};
#pragma unroll
  for (int r = 0; r < 4; r++) l_r[r] = 0.f;

  if (start < end) {
    int qrow = row0 + wl * 16 + m;
    if (qrow >= kend) qrow = row0;
    s8 qf0 = *(const s8*)&qg[(size_t)qrow * DIM + h * DPH + quad * 8];
    s8 qf1 = *(const s8*)&qg[(size_t)qrow * DIM + h * DPH + 32 + quad * 8];

    s8 pk0, pk1, pv0, pv1;
#define PREF(JT)                                                              \
  do {                                                                        \
    pk0 = *(const s8*)&kg[(size_t)((JT) + r0) * DIM + h * DPH + c0];          \
    pk1 = *(const s8*)&kg[(size_t)((JT) + r0 + 32) * DIM + h * DPH + c0];     \
    pv0 = *(const s8*)&vgT[(size_t)(h * DPH + r0) * VPITCH + (JT) + c0];      \
    pv1 = *(const s8*)&vgT[(size_t)(h * DPH + r0 + 32) * VPITCH + (JT) + c0]; \
  } while (0)

    PREF(start);
    for (int jt = start; jt < end; jt += 64) {
      __syncthreads();  // prev tile's LDS readers done
      *(s8*)&k_s[r0 * 72 + c0] = pk0;
      *(s8*)&k_s[(r0 + 32) * 72 + c0] = pk1;
      *(s8*)&v_s[r0 * 72 + c0] = pv0;
      *(s8*)&v_s[(r0 + 32) * 72 + c0] = pv1;
      int jn = jt + 64;
      if (jn < end) PREF(jn);  // overlap next tile's loads with compute
      __syncthreads();

      f4 s_acc[4];
#pragma unroll
      for (int t = 0; t < 4; t++) s_acc[t] = (f4){0.f, 0.f, 0.f, 0.f};
#pragma unroll
      for (int t = 0; t < 4; t++) {
        s8 kb0 = *(s8*)&k_s[(t * 16 + m) * 72 + quad * 8];
        s8 kb1 = *(s8*)&k_s[(t * 16 + m) * 72 + 32 + quad * 8];
        s_acc[t] = __builtin_amdgcn_mfma_f32_16x16x32_bf16(qf0, kb0, s_acc[t], 0, 0, 0);
        s_acc[t] = __builtin_amdgcn_mfma_f32_16x16x32_bf16(qf1, kb1, s_acc[t], 0, 0, 0);
      }

      // p = exp(s*scale) (bounded scores -> shift-free exact), tail-masked.
#pragma unroll
      for (int t = 0; t < 4; t++) {
        bool ok = (jt + t * 16 + m) < kend;
#pragma unroll
        for (int r = 0; r < 4; r++) {
          float p = ok ? __expf(s_acc[t][r] * SCALE) : 0.f;
          l_r[r] += p;
          p_s[(wl * 16 + quad * 4 + r) * 72 + t * 16 + m] = f2bf(p);
        }
      }

#pragma unroll
      for (int kk = 0; kk < 2; kk++) {
        s8 pa = *(s8*)&p_s[(wl * 16 + m) * 72 + kk * 32 + quad * 8];
#pragma unroll
        for (int t = 0; t < 4; t++) {
          s8 vb = *(s8*)&v_s[(t * 16 + m) * 72 + kk * 32 + quad * 8];
          o_acc[t] = __builtin_amdgcn_mfma_f32_16x16x32_bf16(pa, vb, o_acc[t], 0, 0, 0);
        }
      }
    }
#undef PREF
  }

  // Epilogue: write UNNORMALIZED partial O (f32, coalesced 64B segments) +
  // partial l. Empty chunks write zeros so k_out never reads poisoned ws.
  float* Ob = Op + (size_t)sp * GPAD * DIM;
#pragma unroll
  for (int r = 0; r < 4; r++) {
    float lt = l_r[r];
#pragma unroll
    for (int o = 8; o > 0; o >>= 1) lt += __shfl_xor(lt, o, 64);
    int grow = row0 + wl * 16 + quad * 4 + r;
    if (m == 0)
      __builtin_nontemporal_store(lt,
                                  &lp[(size_t)(sp * NHEAD + h) * GPAD + grow]);
#pragma unroll
    for (int t = 0; t < 4; t++)
      __builtin_nontemporal_store(
          o_acc[t][r], &Ob[(size_t)grow * DIM + h * DPH + t * 16 + m]);
  }
}

// ---------------------------------------------------------------------------
// Kernel 4: combine splits + out-proj + LayerNorm. Block = 16 tokens (token
// order). Each thread sums NSPLIT partials for its A-frag row, divides by
// summed l, converts to bf16 frags, then MFMA Wf GEMM + residual + LN.
// Op/lp read NON-TEMPORAL (consumed once, never re-read).
// ---------------------------------------------------------------------------
__global__ __launch_bounds__(256) void k_out(
    const float* __restrict__ Op, const float* __restrict__ lp,
    const int* __restrict__ iperm, const short* __restrict__ WbT,
    const float* __restrict__ x, const float* __restrict__ bfv,
    const float* __restrict__ gamma, const float* __restrict__ beta,
    float* __restrict__ out) {
  int t0 = blockIdx.x * 16;
  int tid = threadIdx.x, wl = tid >> 6, lane = tid & 63;
  int m = lane & 15, quad = lane >> 4;
  __shared__ float h_s[16 * 260];

  int grow = iperm[t0 + m];
  float inv[NHEAD];
#pragma unroll
  for (int h = 0; h < NHEAD; h++) {
    float s = 0.f;
#pragma unroll
    for (int sp = 0; sp < NSPLIT; sp++)
      s += __builtin_nontemporal_load(
          &lp[(size_t)(sp * NHEAD + h) * GPAD + grow]);
    inv[h] = 1.f / s;
  }

  s8 af[8];
#pragma unroll
  for (int kc = 0; kc < 8; kc++) {
    f4 s0 = (f4){0.f, 0.f, 0.f, 0.f}, s1 = (f4){0.f, 0.f, 0.f, 0.f};
#pragma unroll
    for (int sp = 0; sp < NSPLIT; sp++) {
      const float* p =
          Op + ((size_t)sp * GPAD + grow) * DIM + kc * 32 + quad * 8;
      s0 += __builtin_nontemporal_load((const f4*)p);
      s1 += __builtin_nontemporal_load((const f4*)(p + 4));
    }
    float iv = inv[kc >> 1];
#pragma unroll
    for (int j = 0; j < 4; j++) {
      af[kc][j] = f2bf(s0[j] * iv);
      af[kc][4 + j] = f2bf(s1[j] * iv);
    }
  }

  const short* Bp =
      WbT + (size_t)27 * 65536 + (size_t)(wl * 64 + m) * 256 + quad * 8;
  f4 acc[4];
#pragma unroll
  for (int t = 0; t < 4; t++) acc[t] = (f4){0.f, 0.f, 0.f, 0.f};
#pragma unroll
  for (int kc = 0; kc < 8; kc++)
#pragma unroll
    for (int t = 0; t < 4; t++) {
      s8 wb = *(const s8*)(Bp + t * 16 * 256 + kc * 32);
      acc[t] = __builtin_amdgcn_mfma_f32_16x16x32_bf16(af[kc], wb, acc[t], 0, 0, 0);
    }

#pragma unroll
  for (int t = 0; t < 4; t++) {
    int col = wl * 64 + t * 16 + m;
    float bs = bfv[col];
#pragma unroll
    for (int r = 0; r < 4; r++) h_s[(quad * 4 + r) * 260 + col] = acc[t][r] + bs;
  }
  __syncthreads();

#pragma unroll
  for (int rr = 0; rr < 4; rr++) {
    int row = wl * 4 + rr;
    float hv[4];
#pragma unroll
    for (int k2 = 0; k2 < 4; k2++)
      hv[k2] = h_s[row * 260 + lane + 64 * k2] +
               x[(size_t)(t0 + row) * DIM + lane + 64 * k2];
    float mean = wave_sum(hv[0] + hv[1] + hv[2] + hv[3]) * (1.f / 256.f);
    float sq = 0.f;
#pragma unroll
    for (int k2 = 0; k2 < 4; k2++) {
      float dd = hv[k2] - mean;
      sq += dd * dd;
    }
    float rstd = rsqrtf(wave_sum(sq) * (1.f / 256.f) + 1e-5f);
#pragma unroll
    for (int k2 = 0; k2 < 4; k2++) {
      int c = lane + 64 * k2;
      out[(size_t)(t0 + row) * DIM + c] =
          gamma[c] * ((hv[k2] - mean) * rstd) + beta[c];
    }
  }
}

// ---------------------------------------------------------------------------
extern "C" void kernel_launch(void* const* d_in, const int* in_sizes, int n_in,
                              void* d_out, int out_size, void* d_ws,
                              size_t ws_size, hipStream_t stream) {
  const float* x = (const float*)d_in[0];
  const int* label = (const int*)d_in[1];
  const float* Wq = (const float*)d_in[2];
  const float* bq = (const float*)d_in[3];
  const float* Wk = (const float*)d_in[4];
  const float* bk = (const float*)d_in[5];
  const float* Wv = (const float*)d_in[6];
  const float* bv = (const float*)d_in[7];
  const float* Wf = (const float*)d_in[8];
  const float* bfv = (const float*)d_in[9];
  const float* gamma = (const float*)d_in[10];
  const float* beta = (const float*)d_in[11];
  float* out = (float*)d_out;

  // Workspace (~35 MB of 256 MB).
  int* perm = (int*)d_ws;        // 4800 slot
  int* iperm = perm + 4800;      // 4096
  int* gs = iperm + 4096;        // 16
  int* gep = gs + 16;            // 16
  int* st_e = gep + 16;          // 128
  int* st_row = st_e + 128;      // 128
  int* nstp = st_row + 128;      // 8
  short* qg = (short*)((char*)d_ws + 65536);
  short* kg = qg + (size_t)GPAD * DIM;
  short* vgT = kg + (size_t)GPAD * DIM;
  short* WbT = vgT + (size_t)DIM * VPITCH;
  short* xb = WbT + (size_t)28 * 65536;
  float* Op = (float*)(xb + (size_t)N_TOK * DIM);   // [NSPLIT][GPAD][256] f32
  float* lp = Op + (size_t)NSPLIT * GPAD * DIM;     // [NSPLIT][4][GPAD] f32

  hipLaunchKernelGGL(k_prep, dim3(513), dim3(256), 0, stream, x, label, Wq, Wk,
                     Wv, Wf, perm, iperm, gs, gep, st_e, st_row, nstp, WbT, xb);
  hipLaunchKernelGGL(k_proj, dim3(MAXST, 4, 3), dim3(256), 0, stream, xb, WbT,
                     bq, bk, bv, perm, gep, st_e, st_row, nstp, qg, kg, vgT);
  hipLaunchKernelGGL(k_attn, dim3(MAXST, NHEAD, NSPLIT), dim3(256), 0, stream,
                     qg, kg, vgT, gs, gep, st_e, st_row, nstp, Op, lp);
  hipLaunchKernelGGL(k_out, dim3(N_TOK / 16), dim3(256), 0, stream, Op, lp,
                     iperm, WbT, x, bfv, gamma, beta, out);
}

// Round 6
// 139.306 us; speedup vs baseline: 4.7951x; 1.0583x over previous
//
#include <hip/hip_runtime.h>
#include <math.h>

#define N_TOK 4096
#define DIM 256
#define NHEAD 4
#define DPH 64
#define NEXP 9
#define SCALE 0.25f
#define MAXST 80    // 64-row supertiles: <= 64 + 9
#define GPAD 4736   // 64-aligned grouped rows upper bound
#define VPITCH 4736
#define NSPLIT 2    // key-range splits per (supertile, head) — R5's 4 regressed
// exp(x*SCALE) = 2^(x * SCALE*log2(e))
#define EXP2SCALE 0.36067376022224085f

typedef short s8 __attribute__((ext_vector_type(8)));
typedef short s4 __attribute__((ext_vector_type(4)));
typedef float f4 __attribute__((ext_vector_type(4)));

// HW packed f32->bf16 (RNE), 1 VALU op for 2 values; no builtin on gfx950
// (guide T12/m240) so inline asm. Non-volatile: scheduler may CSE/reorder.
static __device__ __forceinline__ unsigned cvt_pk_bf16(float a, float b) {
  unsigned r;
  asm("v_cvt_pk_bf16_f32 %0, %1, %2" : "=v"(r) : "v"(a), "v"(b));
  return r;
}

static __device__ __forceinline__ float exp2_hw(float x) {
  float r;
  asm("v_exp_f32 %0, %1" : "=v"(r) : "v"(x));
  return r;
}

static __device__ __forceinline__ short f2bf(float f) {
  union { float f; unsigned u; } v;
  v.f = f;
  unsigned r = (v.u + 0x7FFFu + ((v.u >> 16) & 1u)) >> 16;
  return (short)r;
}

static __device__ __forceinline__ float wave_sum(float v) {
#pragma unroll
  for (int o = 32; o > 0; o >>= 1) v += __shfl_xor(v, o, 64);
  return v;
}

// ---------------------------------------------------------------------------
// Kernel 1: prep. Block 0: bucket tokens — ATOMIC-FREE build: per-wave ballot
// histogram, LDS cross-wave prefix, deterministic rank scatter. Blocks
// 1..448: W fp32 [d][h] -> WbT bf16 [slab][h][d]. Blocks 449..512: x -> bf16.
// ---------------------------------------------------------------------------
__global__ __launch_bounds__(256) void k_prep(
    const float* __restrict__ x, const int* __restrict__ label,
    const float* __restrict__ Wq, const float* __restrict__ Wk,
    const float* __restrict__ Wv, const float* __restrict__ Wf,
    int* __restrict__ perm, int* __restrict__ iperm, int* __restrict__ gs,
    int* __restrict__ gep, int* __restrict__ st_e, int* __restrict__ st_row,
    int* __restrict__ nstp, short* __restrict__ WbT, short* __restrict__ xb) {
  int b = blockIdx.x;
  int tid = threadIdx.x;
  if (b == 0) {
    __shared__ int cnt_s[4][NEXP];  // per-wave counts
    __shared__ int gsh[NEXP];       // group starts (LDS copy)
    int wl = tid >> 6, lane = tid & 63;
    int lab[16];
#pragma unroll
    for (int i = 0; i < 16; i++) lab[i] = label[wl * 1024 + i * 64 + lane];

    int cw[NEXP];
#pragma unroll
    for (int e = 0; e < NEXP; e++) cw[e] = 0;
#pragma unroll
    for (int i = 0; i < 16; i++)
#pragma unroll
      for (int e = 0; e < NEXP; e++)
        cw[e] += __popcll(__ballot(lab[i] == e));
    if (lane == 0)
#pragma unroll
      for (int e = 0; e < NEXP; e++) cnt_s[wl][e] = cw[e];
    __syncthreads();

    if (tid == 0) {
      int run = 0, ns = 0;
      for (int e = 0; e < NEXP; e++) {
        int tot = cnt_s[0][e] + cnt_s[1][e] + cnt_s[2][e] + cnt_s[3][e];
        gs[e] = run;
        gsh[e] = run;
        int end = run + tot;
        gep[e] = end;
        for (int r = run; r < end; r += 64) {
          st_e[ns] = e;
          st_row[ns] = r;
          ns++;
        }
        run = (end + 63) & ~63;  // 64-align next group start
      }
      *nstp = ns;
    }
    __syncthreads();

    int baseW[NEXP];
#pragma unroll
    for (int e = 0; e < NEXP; e++) {
      int bse = gsh[e];
      for (int w = 0; w < 4; w++)
        if (w < wl) bse += cnt_s[w][e];
      baseW[e] = bse;
    }
    int run2[NEXP];
#pragma unroll
    for (int e = 0; e < NEXP; e++) run2[e] = 0;
#pragma unroll
    for (int i = 0; i < 16; i++) {
      int t = wl * 1024 + i * 64 + lane;
      int lv = lab[i];
      unsigned long long below = (1ull << lane) - 1ull;
      int pos = 0;
#pragma unroll
      for (int e = 0; e < NEXP; e++) {
        unsigned long long mk = __ballot(lv == e);
        if (lv == e) pos = baseW[e] + run2[e] + __popcll(mk & below);
        run2[e] += __popcll(mk);
      }
      perm[pos] = t;
      iperm[t] = pos;
    }
  } else if (b <= 448) {
    // Weight transpose: slabs 0-8 Wq, 9-17 Wk, 18-26 Wv, 27 Wf; 16 tiles/slab.
    __shared__ short tile[64 * 68];
    int vt = b - 1;
    int slab = vt >> 4;
    const float* src = (slab < 9)    ? Wq + (size_t)slab * 65536
                       : (slab < 18) ? Wk + (size_t)(slab - 9) * 65536
                       : (slab < 27) ? Wv + (size_t)(slab - 18) * 65536
                                     : Wf;
    int xy = vt & 15;
    int d0 = (xy >> 2) * 64, h0 = (xy & 3) * 64;
    int rl = tid >> 4;
    int hh = (tid & 15) * 4;
#pragma unroll
    for (int p = 0; p < 4; p++) {
      int dl = p * 16 + rl;
      float4 v = *(const float4*)(src + (size_t)(d0 + dl) * 256 + h0 + hh);
      union { s4 v; unsigned u[2]; } o;
      o.u[0] = cvt_pk_bf16(v.x, v.y);
      o.u[1] = cvt_pk_bf16(v.z, v.w);
      *(s4*)&tile[dl * 68 + hh] = o.v;
    }
    __syncthreads();
    int h = tid >> 2, dq = (tid & 3) * 16;
    s8 pa, pb;
#pragma unroll
    for (int i = 0; i < 8; i++) {
      pa[i] = tile[(dq + i) * 68 + h];
      pb[i] = tile[(dq + 8 + i) * 68 + h];
    }
    short* dst = WbT + (size_t)slab * 65536 + (size_t)(h0 + h) * 256 + d0 + dq;
    *(s8*)dst = pa;
    *(s8*)(dst + 8) = pb;
  } else {
    // x -> bf16, token order.
    int tok = (b - 449) * 64 + (tid >> 2);
    int qd = (tid & 3) * 64;
    const float* src = x + (size_t)tok * DIM + qd;
    short* dst = xb + (size_t)tok * DIM + qd;
#pragma unroll
    for (int i = 0; i < 16; i++) {
      float4 v = *(const float4*)(src + i * 4);
      union { s4 v; unsigned u[2]; } o;
      o.u[0] = cvt_pk_bf16(v.x, v.y);
      o.u[1] = cvt_pk_bf16(v.z, v.w);
      *(s4*)(dst + i * 4) = o.v;
    }
  }
}

// ---------------------------------------------------------------------------
// Kernel 2: MFMA QKV projection. Grid (supertile, colblock 0..3, mtx 0..2);
// wave = 16 grouped rows x 64 cols; A-frags gathered via perm (clamped).
// ---------------------------------------------------------------------------
__global__ __launch_bounds__(256) void k_proj(
    const short* __restrict__ xb, const short* __restrict__ WbT,
    const float* __restrict__ bq, const float* __restrict__ bk,
    const float* __restrict__ bv, const int* __restrict__ perm,
    const int* __restrict__ gep, const int* __restrict__ st_e,
    const int* __restrict__ st_row, const int* __restrict__ nstp,
    short* __restrict__ qg, short* __restrict__ kg, short* __restrict__ vgT) {
  int b = blockIdx.x;
  if (b >= *nstp) return;
  int gy = blockIdx.y;
  int mtx = blockIdx.z;
  int e = st_e[b];
  int row0 = st_row[b];
  int g1 = gep[e];
  int tid = threadIdx.x, wl = tid >> 6, lane = tid & 63;
  int m = lane & 15, quad = lane >> 4;

  __shared__ short st_s[4][16 * 72];  // per-wave store-transpose buffer

  int row = row0 + wl * 16 + m;
  int pr = perm[(row < g1) ? row : row0];  // clamp padding rows
  const short* Ap = xb + (size_t)pr * DIM + quad * 8;
  const short* Bp = WbT + (size_t)(mtx * 9 + e) * 65536 +
                    (size_t)(gy * 64 + m) * 256 + quad * 8;
  const float* bias = (mtx == 0) ? bq : (mtx == 1) ? bk : bv;

  s8 ac = *(const s8*)Ap;
  s8 bc[4];
#pragma unroll
  for (int t = 0; t < 4; t++) bc[t] = *(const s8*)(Bp + t * 16 * 256);
  f4 acc[4];
#pragma unroll
  for (int t = 0; t < 4; t++) acc[t] = (f4){0.f, 0.f, 0.f, 0.f};
#pragma unroll
  for (int kc = 0; kc < 8; kc++) {
    s8 an = ac;
    s8 bn[4] = {bc[0], bc[1], bc[2], bc[3]};
    if (kc < 7) {
      an = *(const s8*)(Ap + (kc + 1) * 32);
#pragma unroll
      for (int t = 0; t < 4; t++)
        bn[t] = *(const s8*)(Bp + t * 16 * 256 + (kc + 1) * 32);
    }
#pragma unroll
    for (int t = 0; t < 4; t++)
      acc[t] = __builtin_amdgcn_mfma_f32_16x16x32_bf16(ac, bc[t], acc[t], 0, 0, 0);
    ac = an;
#pragma unroll
    for (int t = 0; t < 4; t++) bc[t] = bn[t];
  }

  if (mtx == 2) {
    // vgT[col][grow]: quad owns 4 consecutive grows per col -> 8B s4 stores.
#pragma unroll
    for (int t = 0; t < 4; t++) {
      int col = gy * 64 + t * 16 + m;
      float bs = bias[e * DIM + col];
      union { s4 v; unsigned u[2]; } o;
      o.u[0] = cvt_pk_bf16(acc[t][0] + bs, acc[t][1] + bs);
      o.u[1] = cvt_pk_bf16(acc[t][2] + bs, acc[t][3] + bs);
      *(s4*)&vgT[(size_t)col * VPITCH + row0 + wl * 16 + quad * 4] = o.v;
    }
  } else {
    // LDS transpose: C-layout -> [row][col] bf16, then coalesced stores.
    short* ws = st_s[wl];
#pragma unroll
    for (int t = 0; t < 4; t++) {
      int col = gy * 64 + t * 16 + m;
      float bs = bias[e * DIM + col];
      unsigned p01 = cvt_pk_bf16(acc[t][0] + bs, acc[t][1] + bs);
      unsigned p23 = cvt_pk_bf16(acc[t][2] + bs, acc[t][3] + bs);
      int base = quad * 4;
      ws[(base + 0) * 72 + t * 16 + m] = (short)p01;
      ws[(base + 1) * 72 + t * 16 + m] = (short)(p01 >> 16);
      ws[(base + 2) * 72 + t * 16 + m] = (short)p23;
      ws[(base + 3) * 72 + t * 16 + m] = (short)(p23 >> 16);
    }
    // same-wave LDS ordering (compiler inserts lgkmcnt)
    int rr = lane >> 2, cg2 = (lane & 3) * 16;
    s8 v0 = *(s8*)&ws[rr * 72 + cg2];
    s8 v1 = *(s8*)&ws[rr * 72 + cg2 + 8];
    short* dst = ((mtx == 1) ? kg : qg) +
                 (size_t)(row0 + wl * 16 + rr) * DIM + gy * 64 + cg2;
    *(s8*)dst = v0;
    *(s8*)(dst + 8) = v1;
  }
}

// ---------------------------------------------------------------------------
// Kernel 3: split-K MFMA flash attention (single-buffered K/V staging).
// Fixed-shift softmax -> additive partials; k_out combines. Softmax VALU
// diet: premultiplied v_exp_f32 (1 mul + 1 exp vs 2 mul + 1 exp) and
// v_cvt_pk_bf16_f32 pairs (1 op/2 vals vs 4 ops/val software RNE).
// ---------------------------------------------------------------------------
__global__ __launch_bounds__(256) void k_attn(
    const short* __restrict__ qg, const short* __restrict__ kg,
    const short* __restrict__ vgT, const int* __restrict__ gs,
    const int* __restrict__ gep, const int* __restrict__ st_e,
    const int* __restrict__ st_row, const int* __restrict__ nstp,
    float* __restrict__ Op, float* __restrict__ lp) {
  int b = blockIdx.x;
  if (b >= *nstp) return;
  int h = blockIdx.y;
  int sp = blockIdx.z;
  int e = st_e[b];
  int row0 = st_row[b];
  int g0 = gs[e], kend = gep[e];
  int ntiles = (kend - g0 + 63) >> 6;
  int tpc = (ntiles + NSPLIT - 1) / NSPLIT;
  int t0i = sp * tpc;
  int t1i = min(ntiles, t0i + tpc);
  int start = g0 + t0i * 64, end = g0 + t1i * 64;

  int tid = threadIdx.x;
  int wl = tid >> 6, lane = tid & 63;
  int m = lane & 15, quad = lane >> 4;
  int r0 = tid >> 3;
  int c0 = (tid & 7) * 8;

  __shared__ short k_s[64 * 72];      // [key][dph]
  __shared__ short v_s[64 * 72];      // [dph][key] (transposed)
  __shared__ short p_s[4 * 16 * 72];  // per-wave [qrow][key]

  f4 o_acc[4];
  float l_r[4];
#pragma unroll
  for (int t = 0; t < 4; t++) o_acc[t] = (f4){0.f, 0.f, 0.f, 0.f};
#pragma unroll
  for (int r = 0; r < 4; r++) l_r[r] = 0.f;

  if (start < end) {
    int qrow = row0 + wl * 16 + m;
    if (qrow >= kend) qrow = row0;
    s8 qf0 = *(const s8*)&qg[(size_t)qrow * DIM + h * DPH + quad * 8];
    s8 qf1 = *(const s8*)&qg[(size_t)qrow * DIM + h * DPH + 32 + quad * 8];

    s8 pk0, pk1, pv0, pv1;
#define PREF(JT)                                                              \
  do {                                                                        \
    pk0 = *(const s8*)&kg[(size_t)((JT) + r0) * DIM + h * DPH + c0];          \
    pk1 = *(const s8*)&kg[(size_t)((JT) + r0 + 32) * DIM + h * DPH + c0];     \
    pv0 = *(const s8*)&vgT[(size_t)(h * DPH + r0) * VPITCH + (JT) + c0];      \
    pv1 = *(const s8*)&vgT[(size_t)(h * DPH + r0 + 32) * VPITCH + (JT) + c0]; \
  } while (0)

    PREF(start);
    for (int jt = start; jt < end; jt += 64) {
      __syncthreads();  // prev tile's LDS readers done
      *(s8*)&k_s[r0 * 72 + c0] = pk0;
      *(s8*)&k_s[(r0 + 32) * 72 + c0] = pk1;
      *(s8*)&v_s[r0 * 72 + c0] = pv0;
      *(s8*)&v_s[(r0 + 32) * 72 + c0] = pv1;
      int jn = jt + 64;
      if (jn < end) PREF(jn);  // overlap next tile's loads with compute
      __syncthreads();

      f4 s_acc[4];
#pragma unroll
      for (int t = 0; t < 4; t++) s_acc[t] = (f4){0.f, 0.f, 0.f, 0.f};
#pragma unroll
      for (int t = 0; t < 4; t++) {
        s8 kb0 = *(s8*)&k_s[(t * 16 + m) * 72 + quad * 8];
        s8 kb1 = *(s8*)&k_s[(t * 16 + m) * 72 + 32 + quad * 8];
        s_acc[t] = __builtin_amdgcn_mfma_f32_16x16x32_bf16(qf0, kb0, s_acc[t], 0, 0, 0);
        s_acc[t] = __builtin_amdgcn_mfma_f32_16x16x32_bf16(qf1, kb1, s_acc[t], 0, 0, 0);
      }

      // p = exp(s*scale) (bounded scores -> shift-free exact), tail-masked.
#pragma unroll
      for (int t = 0; t < 4; t++) {
        bool ok = (jt + t * 16 + m) < kend;
        float pv[4];
#pragma unroll
        for (int r = 0; r < 4; r++) {
          float p = ok ? exp2_hw(s_acc[t][r] * EXP2SCALE) : 0.f;
          l_r[r] += p;
          pv[r] = p;
        }
        unsigned p01 = cvt_pk_bf16(pv[0], pv[1]);
        unsigned p23 = cvt_pk_bf16(pv[2], pv[3]);
        int base = wl * 16 + quad * 4;
        int col = t * 16 + m;
        p_s[(base + 0) * 72 + col] = (short)p01;
        p_s[(base + 1) * 72 + col] = (short)(p01 >> 16);
        p_s[(base + 2) * 72 + col] = (short)p23;
        p_s[(base + 3) * 72 + col] = (short)(p23 >> 16);
      }

#pragma unroll
      for (int kk = 0; kk < 2; kk++) {
        s8 pa = *(s8*)&p_s[(wl * 16 + m) * 72 + kk * 32 + quad * 8];
#pragma unroll
        for (int t = 0; t < 4; t++) {
          s8 vb = *(s8*)&v_s[(t * 16 + m) * 72 + kk * 32 + quad * 8];
          o_acc[t] = __builtin_amdgcn_mfma_f32_16x16x32_bf16(pa, vb, o_acc[t], 0, 0, 0);
        }
      }
    }
#undef PREF
  }

  // Epilogue: write UNNORMALIZED partial O (f32, coalesced 64B segments) +
  // partial l. Empty chunks write zeros so k_out never reads poisoned ws.
  float* Ob = Op + (size_t)sp * GPAD * DIM;
#pragma unroll
  for (int r = 0; r < 4; r++) {
    float lt = l_r[r];
#pragma unroll
    for (int o = 8; o > 0; o >>= 1) lt += __shfl_xor(lt, o, 64);
    int grow = row0 + wl * 16 + quad * 4 + r;
    if (m == 0) lp[(size_t)(sp * NHEAD + h) * GPAD + grow] = lt;
#pragma unroll
    for (int t = 0; t < 4; t++)
      Ob[(size_t)grow * DIM + h * DPH + t * 16 + m] = o_acc[t][r];
  }
}

// ---------------------------------------------------------------------------
// Kernel 4: combine splits + out-proj + LayerNorm. Block = 16 tokens (token
// order). Each thread sums NSPLIT partials for its A-frag row, divides by
// summed l, converts to bf16 frags via cvt_pk (adjacent shorts -> free
// pack), then MFMA Wf GEMM + residual + LN.
// ---------------------------------------------------------------------------
__global__ __launch_bounds__(256) void k_out(
    const float* __restrict__ Op, const float* __restrict__ lp,
    const int* __restrict__ iperm, const short* __restrict__ WbT,
    const float* __restrict__ x, const float* __restrict__ bfv,
    const float* __restrict__ gamma, const float* __restrict__ beta,
    float* __restrict__ out) {
  int t0 = blockIdx.x * 16;
  int tid = threadIdx.x, wl = tid >> 6, lane = tid & 63;
  int m = lane & 15, quad = lane >> 4;
  __shared__ float h_s[16 * 260];

  int grow = iperm[t0 + m];
  float inv[NHEAD];
#pragma unroll
  for (int h = 0; h < NHEAD; h++) {
    float s = 0.f;
#pragma unroll
    for (int sp = 0; sp < NSPLIT; sp++)
      s += lp[(size_t)(sp * NHEAD + h) * GPAD + grow];
    inv[h] = 1.f / s;
  }

  s8 af[8];
#pragma unroll
  for (int kc = 0; kc < 8; kc++) {
    f4 s0 = (f4){0.f, 0.f, 0.f, 0.f}, s1 = (f4){0.f, 0.f, 0.f, 0.f};
#pragma unroll
    for (int sp = 0; sp < NSPLIT; sp++) {
      const float* p =
          Op + ((size_t)sp * GPAD + grow) * DIM + kc * 32 + quad * 8;
      s0 += *(const f4*)p;
      s1 += *(const f4*)(p + 4);
    }
    float iv = inv[kc >> 1];
    union { s8 v; unsigned u[4]; } a;
    a.u[0] = cvt_pk_bf16(s0[0] * iv, s0[1] * iv);
    a.u[1] = cvt_pk_bf16(s0[2] * iv, s0[3] * iv);
    a.u[2] = cvt_pk_bf16(s1[0] * iv, s1[1] * iv);
    a.u[3] = cvt_pk_bf16(s1[2] * iv, s1[3] * iv);
    af[kc] = a.v;
  }

  const short* Bp =
      WbT + (size_t)27 * 65536 + (size_t)(wl * 64 + m) * 256 + quad * 8;
  f4 acc[4];
#pragma unroll
  for (int t = 0; t < 4; t++) acc[t] = (f4){0.f, 0.f, 0.f, 0.f};
#pragma unroll
  for (int kc = 0; kc < 8; kc++)
#pragma unroll
    for (int t = 0; t < 4; t++) {
      s8 wb = *(const s8*)(Bp + t * 16 * 256 + kc * 32);
      acc[t] = __builtin_amdgcn_mfma_f32_16x16x32_bf16(af[kc], wb, acc[t], 0, 0, 0);
    }

#pragma unroll
  for (int t = 0; t < 4; t++) {
    int col = wl * 64 + t * 16 + m;
    float bs = bfv[col];
#pragma unroll
    for (int r = 0; r < 4; r++) h_s[(quad * 4 + r) * 260 + col] = acc[t][r] + bs;
  }
  __syncthreads();

#pragma unroll
  for (int rr = 0; rr < 4; rr++) {
    int row = wl * 4 + rr;
    float hv[4];
#pragma unroll
    for (int k2 = 0; k2 < 4; k2++)
      hv[k2] = h_s[row * 260 + lane + 64 * k2] +
               x[(size_t)(t0 + row) * DIM + lane + 64 * k2];
    float mean = wave_sum(hv[0] + hv[1] + hv[2] + hv[3]) * (1.f / 256.f);
    float sq = 0.f;
#pragma unroll
    for (int k2 = 0; k2 < 4; k2++) {
      float dd = hv[k2] - mean;
      sq += dd * dd;
    }
    float rstd = rsqrtf(wave_sum(sq) * (1.f / 256.f) + 1e-5f);
#pragma unroll
    for (int k2 = 0; k2 < 4; k2++) {
      int c = lane + 64 * k2;
      out[(size_t)(t0 + row) * DIM + c] =
          gamma[c] * ((hv[k2] - mean) * rstd) + beta[c];
    }
  }
}

// ---------------------------------------------------------------------------
extern "C" void kernel_launch(void* const* d_in, const int* in_sizes, int n_in,
                              void* d_out, int out_size, void* d_ws,
                              size_t ws_size, hipStream_t stream) {
  const float* x = (const float*)d_in[0];
  const int* label = (const int*)d_in[1];
  const float* Wq = (const float*)d_in[2];
  const float* bq = (const float*)d_in[3];
  const float* Wk = (const float*)d_in[4];
  const float* bk = (const float*)d_in[5];
  const float* Wv = (const float*)d_in[6];
  const float* bv = (const float*)d_in[7];
  const float* Wf = (const float*)d_in[8];
  const float* bfv = (const float*)d_in[9];
  const float* gamma = (const float*)d_in[10];
  const float* beta = (const float*)d_in[11];
  float* out = (float*)d_out;

  // Workspace (~25 MB of 256 MB).
  int* perm = (int*)d_ws;        // 4800 slot
  int* iperm = perm + 4800;      // 4096
  int* gs = iperm + 4096;        // 16
  int* gep = gs + 16;            // 16
  int* st_e = gep + 16;          // 128
  int* st_row = st_e + 128;      // 128
  int* nstp = st_row + 128;      // 8
  short* qg = (short*)((char*)d_ws + 65536);
  short* kg = qg + (size_t)GPAD * DIM;
  short* vgT = kg + (size_t)GPAD * DIM;
  short* WbT = vgT + (size_t)DIM * VPITCH;
  short* xb = WbT + (size_t)28 * 65536;
  float* Op = (float*)(xb + (size_t)N_TOK * DIM);   // [NSPLIT][GPAD][256] f32
  float* lp = Op + (size_t)NSPLIT * GPAD * DIM;     // [NSPLIT][4][GPAD] f32

  hipLaunchKernelGGL(k_prep, dim3(513), dim3(256), 0, stream, x, label, Wq, Wk,
                     Wv, Wf, perm, iperm, gs, gep, st_e, st_row, nstp, WbT, xb);
  hipLaunchKernelGGL(k_proj, dim3(MAXST, 4, 3), dim3(256), 0, stream, xb, WbT,
                     bq, bk, bv, perm, gep, st_e, st_row, nstp, qg, kg, vgT);
  hipLaunchKernelGGL(k_attn, dim3(MAXST, NHEAD, NSPLIT), dim3(256), 0, stream,
                     qg, kg, vgT, gs, gep, st_e, st_row, nstp, Op, lp);
  hipLaunchKernelGGL(k_out, dim3(N_TOK / 16), dim3(256), 0, stream, Op, lp,
                     iperm, WbT, x, bfv, gamma, beta, out);
}